// Round 6
// baseline (299.442 us; speedup 1.0000x reference)
//
#include <hip/hip_runtime.h>
#include <math.h>

#define HH 128
#define WW 128
#define HWSZ 16384

typedef __attribute__((ext_vector_type(8))) _Float16 h8;
typedef __attribute__((ext_vector_type(2))) _Float16 h2;
typedef __attribute__((ext_vector_type(4))) float f32x4;
typedef __attribute__((ext_vector_type(2))) float f32x2;
typedef unsigned short ushort;

// fp16 conversion helpers (RNE via scalar cast)
__device__ __forceinline__ ushort f2h(float f) {
    _Float16 h = (_Float16)f;
    ushort u;
    __builtin_memcpy(&u, &h, 2);
    return u;
}
// pack two floats -> packed fp16 dword (lo in [15:0], hi in [31:16])
__device__ __forceinline__ unsigned f2h2(float lo, float hi) {
    h2 r;
    r.x = (_Float16)lo;
    r.y = (_Float16)hi;
    unsigned u;
    __builtin_memcpy(&u, &r, 4);
    return u;
}
// unpack 2 packed fp16 (one dword) to float2
__device__ __forceinline__ f32x2 unpk_h2(unsigned u) {
    h2 h;
    __builtin_memcpy(&h, &u, 4);
    return (f32x2){(float)h.x, (float)h.y};
}

// ---- merged weight prep: wpad1 | wpad2 | woff1 | woff2 in one launch ----
__global__ __launch_bounds__(256) void prep_weights(
    const float* __restrict__ w1, const float* __restrict__ w2,
    const float* __restrict__ w_off1, const float* __restrict__ w_mod1,
    const float* __restrict__ w_off2, const float* __restrict__ w_mod2,
    ushort* __restrict__ Wt1, ushort* __restrict__ Wt2,
    ushort* __restrict__ Wo1, ushort* __restrict__ Wo2) {
    int bid = blockIdx.x, tid = threadIdx.x;
    if (bid < 336) {
        int i = bid * 256 + tid;
        int o = i / 672, kq = i % 672;
        int k = kq / 72, c = kq % 72;
        float v = (k < 9 && c < 64) ? w1[(o * 64 + c) * 9 + k] : 0.f;
        Wt1[i] = f2h(v);
    } else if (bid < 960) {
        int i = (bid - 336) * 256 + tid;
        int o = i / 1248, kq = i % 1248;
        int k = kq / 136, c = kq % 136;
        float v = (k < 9 && c < 128) ? w2[(o * 128 + c) * 9 + k] : 0.f;
        Wt2[i] = f2h(v);
    } else if (bid < 1032) {
        int i = (bid - 960) * 256 + tid;  // < 32*576
        int o = i / 576, kap = i % 576;
        int k = kap / 64, c = kap % 64;
        float v = 0.f;
        if (o < 18) v = w_off1[(o * 64 + c) * 9 + k];
        else if (o < 27) v = w_mod1[((o - 18) * 64 + c) * 9 + k];
        Wo1[i] = f2h(v);
    } else {
        int i = (bid - 1032) * 256 + tid;  // < 32*1152
        int o = i / 1152, kap = i % 1152;
        int k = kap / 128, c = kap % 128;
        float v = 0.f;
        if (o < 18) v = w_off2[(o * 128 + c) * 9 + k];
        else if (o < 27) v = w_mod2[((o - 18) * 128 + c) * 9 + k];
        Wo2[i] = f2h(v);
    }
}

// ---- NCHW fp32 -> NHWC fp16 converter (tiled transpose) ----
template <int C>
__global__ __launch_bounds__(256) void nhwc_cvt(const float* __restrict__ xin,
                                                unsigned* __restrict__ xout) {
    __shared__ float tile[64][C + 1];
    const int m0 = blockIdx.x * 64;
    const int b = m0 >> 14;
    const int hw0 = m0 & 16383;
    const int t = threadIdx.x;
    const int pr = t & 63, cr = t >> 6;
#pragma unroll
    for (int it = 0; it < C / 4; ++it) {
        int c = it * 4 + cr;
        tile[pr][c] = xin[(((size_t)(b * C + c)) << 14) + hw0 + pr];
    }
    __syncthreads();
    constexpr int CH = C / 2;
#pragma unroll
    for (int it = 0; it < 64 * CH / 256; ++it) {
        int slot = it * 256 + t;
        int p = slot / CH, cc = slot % CH;
        xout[(size_t)(m0 + p) * CH + cc] =
            f2h2(tile[p][2 * cc], tile[p][2 * cc + 1]);
    }
}

// ---- elementwise bn finalize + norm/relu on raw NHWC fp16 ----
__global__ __launch_bounds__(256) void bn_apply_ew(
    const unsigned* __restrict__ xin, const float* __restrict__ praw,
    unsigned* __restrict__ xout) {
    __shared__ float lstats[256];
    if (threadIdx.x < 128) {
        int c = threadIdx.x;
        float s = 0.f, q = 0.f;
#pragma unroll
        for (int r = 0; r < 8; ++r) {
            s += praw[r * 256 + c];
            q += praw[r * 256 + 128 + c];
        }
        float mean = s / 65536.f;
        float var = q / 65536.f - mean * mean;
        lstats[c] = mean;
        lstats[128 + c] = rsqrtf(var + 1e-5f);
    }
    __syncthreads();
    int i = blockIdx.x * 256 + threadIdx.x;  // uint4 index (4 dwords = 8 ch)
    uint4 v = ((const uint4*)xin)[i];
    int c0 = ((i * 4) & 63) * 2;  // 64 dwords per pixel (128 ch)
    unsigned ov[4];
    unsigned in[4] = {v.x, v.y, v.z, v.w};
#pragma unroll
    for (int d = 0; d < 4; ++d) {
        int c = c0 + 2 * d;
        f32x2 f = unpk_h2(in[d]);
        float a = fmaxf(0.f, (f.x - lstats[c]) * lstats[128 + c]);
        float b2 = fmaxf(0.f, (f.y - lstats[c + 1]) * lstats[128 + c + 1]);
        ov[d] = f2h2(a, b2);
    }
    ((uint4*)xout)[i] = uint4{ov[0], ov[1], ov[2], ov[3]};
}

// ---- offset/mod conv: NHWC-fp16 direct A-fragment MFMA GEMM ----
// also zeroes the bn praw replicas (blocks 0..7) for the following deform.
template <int C>
__global__ __launch_bounds__(256) void offmod_nhwc(
    const ushort* __restrict__ xh, const ushort* __restrict__ wt,
    const float* __restrict__ b_off, const float* __restrict__ b_mod,
    float* __restrict__ dyb, float* __restrict__ dxb, float* __restrict__ mob,
    float* __restrict__ praw) {
    constexpr int K = C * 9;
    if (blockIdx.x < 8) praw[blockIdx.x * 256 + threadIdx.x] = 0.f;
    const int m0 = blockIdx.x * 64;
    const int b = m0 >> 14;
    const int hw0 = m0 & 16383;
    const int h = hw0 >> 7;
    const int w0 = hw0 & 127;
    const int tid = threadIdx.x;
    const int lane = tid & 63, wv = tid >> 6;
    const int n16 = lane & 15, quad = lane >> 4;
    const int p = wv * 16 + n16;
    const int w = w0 + p;

    int tbase[9];
    bool tval[9];
#pragma unroll
    for (int k = 0; k < 9; ++k) {
        int yy = h + k / 3 - 1, xx = w + k % 3 - 1;
        tval[k] = ((unsigned)yy < 128u) && ((unsigned)xx < 128u);
        int cy = min(max(yy, 0), 127), cx = min(max(xx, 0), 127);
        tbase[k] = ((b << 14) + (cy << 7) + cx) * C + quad * 8;
    }

    f32x4 acc[2];
    acc[0] = (f32x4){0.f, 0.f, 0.f, 0.f};
    acc[1] = (f32x4){0.f, 0.f, 0.f, 0.f};

    const ushort* b0p = wt + (size_t)n16 * K + quad * 8;
    const ushort* b1p = wt + (size_t)(16 + n16) * K + quad * 8;

#pragma unroll
    for (int s = 0; s < K / 32; ++s) {
        const int k = (s * 32) / C;
        const int c0 = (s * 32) % C;
        h8 a = {0, 0, 0, 0, 0, 0, 0, 0};
        if (tval[k]) a = *(const h8*)(xh + (size_t)tbase[k] + c0);
        const h8 bv0 = *(const h8*)(b0p + s * 32);
        const h8 bv1 = *(const h8*)(b1p + s * 32);
        acc[0] = __builtin_amdgcn_mfma_f32_16x16x32_f16(a, bv0, acc[0], 0, 0, 0);
        acc[1] = __builtin_amdgcn_mfma_f32_16x16x32_f16(a, bv1, acc[1], 0, 0, 0);
    }

    __shared__ float sm[32 * 65];
#pragma unroll
    for (int nt = 0; nt < 2; ++nt) {
        int n = nt * 16 + n16;
        int pb = wv * 16 + quad * 4;
#pragma unroll
        for (int r = 0; r < 4; ++r) sm[n * 65 + pb + r] = acc[nt][r];
    }
    __syncthreads();
    {
        int n = tid >> 3, i8 = tid & 7;
        if (n < 27) {
            const float* sp = sm + n * 65 + i8 * 8;
            int px = hw0 + i8 * 8;
            if (n < 18) {
                int k = n >> 1;
                float bias = b_off[n];
                float* dst =
                    ((n & 1) ? dxb : dyb) + (((size_t)(b * 9 + k)) << 14) + px;
#pragma unroll
                for (int j = 0; j < 8; j += 4) {
                    float4 v = make_float4(sp[j] + bias, sp[j + 1] + bias,
                                           sp[j + 2] + bias, sp[j + 3] + bias);
                    *(float4*)(dst + j) = v;
                }
            } else {
                float bias = b_mod[n - 18];
                float* dst = mob + (((size_t)(b * 9 + (n - 18))) << 14) + px;
#pragma unroll
                for (int j = 0; j < 8; j += 4) {
                    float4 v;
                    v.x = 2.f / (1.f + expf(-(sp[j] + bias)));
                    v.y = 2.f / (1.f + expf(-(sp[j + 1] + bias)));
                    v.z = 2.f / (1.f + expf(-(sp[j + 2] + bias)));
                    v.w = 2.f / (1.f + expf(-(sp[j + 3] + bias)));
                    *(float4*)(dst + j) = v;
                }
            }
        }
    }
}

// ---- deformable conv v3 (stage 1): PIX=32, 8 blocks/CU (19.8KB LDS),
// XOR-swizzled LDS, packed gather table, XCD swizzle, setprio. ----
template <int C>
__global__ __launch_bounds__(256, 8) void deform_mfma3(
    const ushort* __restrict__ xh, const float* __restrict__ dyb,
    const float* __restrict__ dxb, const float* __restrict__ mob,
    const ushort* __restrict__ wt, unsigned* __restrict__ xout,
    float* __restrict__ praw) {
    constexpr int PIX = 32;
    constexpr int NCH = C / 8;   // 16B chunks per row
    constexpr int NCC = C / 8;
    constexpr int NIT = PIX * NCC / 256;
    constexpr int HNIT = (NIT >= 2) ? NIT / 2 : 1;
    constexpr int SH = (C / 32) / 2 > 0 ? (C / 32) / 2 : 1;
    constexpr int CPW = C + 8;
    constexpr int KP = ((9 * CPW + 31) / 32) * 32;
    constexpr int ABUF = PIX * C;  // ushorts, no pad (XOR swizzle instead)
    constexpr int LOOPB = 2 * ABUF * 2 + PIX * 9 * 4 + PIX * 9 * 8;
    constexpr int EPIB = 128 * (PIX + 1) * 4;
    constexpr int SMEMB = LOOPB > EPIB ? LOOPB : EPIB;

    __shared__ __align__(16) char smem_raw[SMEMB];
    ushort* abuf0 = (ushort*)smem_raw;
    ushort* abuf1 = abuf0 + ABUF;
    int* tbl = (int*)(abuf0 + 2 * ABUF);
    unsigned* twl = (unsigned*)(smem_raw + 2 * ABUF * 2 + PIX * 9 * 4);

    // XCD-contiguous swizzle: each XCD owns a contiguous 1/8 of the image.
    const int bid = (blockIdx.x & 7) * (gridDim.x >> 3) + (blockIdx.x >> 3);
    const int m0 = bid * PIX;
    const int b = m0 >> 14;
    const int hw0 = m0 & 16383;
    const int h = hw0 >> 7, w0 = hw0 & 127;
    const int tid = threadIdx.x;
    const int lane = tid & 63, wv = tid >> 6;
    const int n16 = lane & 15, quad = lane >> 4;
    const int xr = n16 & (NCH - 1);

    for (int r = tid; r < PIX * 9; r += 256) {
        int p = r & (PIX - 1), k = r >> 5;
        int oi = ((b * 9 + k) << 14) + hw0 + p;
        float py = (float)(h + k / 3 - 1) + dyb[oi];
        float px = (float)(w0 + p + k % 3 - 1) + dxb[oi];
        float mv = mob[oi];
        float y0f = floorf(py), x0f = floorf(px);
        float wy = py - y0f, wx = px - x0f;
        int y0 = (int)y0f, x0 = (int)x0f;
        int y1 = y0 + 1, x1 = x0 + 1;
        float f00 = (1.f - wy) * (1.f - wx) *
                    (((unsigned)y0 < 128u && (unsigned)x0 < 128u) ? mv : 0.f);
        float f01 = (1.f - wy) * wx *
                    (((unsigned)y0 < 128u && (unsigned)x1 < 128u) ? mv : 0.f);
        float f10 = wy * (1.f - wx) *
                    (((unsigned)y1 < 128u && (unsigned)x0 < 128u) ? mv : 0.f);
        float f11 = wy * wx *
                    (((unsigned)y1 < 128u && (unsigned)x1 < 128u) ? mv : 0.f);
        int cy0 = min(max(y0, 0), 127), cy1 = min(max(y1, 0), 127);
        int cx0 = min(max(x0, 0), 127), cx1 = min(max(x1, 0), 127);
        int base00 = (((b << 14) + (cy0 << 7) + cx0)) * C;
        int flags = ((cy1 != cy0) ? 2 : 0) | ((cx1 != cx0) ? 1 : 0);
        int s = p * 9 + k;
        tbl[s] = base00 | flags;
        twl[2 * s] = f2h2(f00, f01);
        twl[2 * s + 1] = f2h2(f10, f11);
    }
    __syncthreads();

    auto issue_loads = [&](int kc, int it0, uint4 (&q)[HNIT][4],
                           uint2 (&fw)[HNIT]) {
#pragma unroll
        for (int j = 0; j < HNIT; ++j) {
            int e = (it0 + j) * 256 + tid;
            int p = e / NCC, cc = e % NCC;
            int s = p * 9 + kc;
            int ent = tbl[s];
            fw[j] = *(const uint2*)&twl[2 * s];
            int base = ent & ~3;
            int dxo = (ent & 1) ? C : 0;
            int dyo = (ent & 2) ? (C << 7) : 0;
            const ushort* pp = xh + (size_t)base + cc * 8;
            q[j][0] = *(const uint4*)(pp);
            q[j][1] = *(const uint4*)(pp + dxo);
            q[j][2] = *(const uint4*)(pp + dyo);
            q[j][3] = *(const uint4*)(pp + dyo + dxo);
        }
    };
    auto interp_write = [&](ushort* dst, int it0, uint4 (&q)[HNIT][4],
                            uint2 (&fw)[HNIT]) {
#pragma unroll
        for (int j = 0; j < HNIT; ++j) {
            int e = (it0 + j) * 256 + tid;
            int p = e / NCC, cc = e % NCC;
            h2 w01, w23;
            __builtin_memcpy(&w01, &fw[j].x, 4);
            __builtin_memcpy(&w23, &fw[j].y, 4);
            h8 F0 = {w01.x, w01.x, w01.x, w01.x, w01.x, w01.x, w01.x, w01.x};
            h8 F1 = {w01.y, w01.y, w01.y, w01.y, w01.y, w01.y, w01.y, w01.y};
            h8 F2 = {w23.x, w23.x, w23.x, w23.x, w23.x, w23.x, w23.x, w23.x};
            h8 F3 = {w23.y, w23.y, w23.y, w23.y, w23.y, w23.y, w23.y, w23.y};
            h8 a0, a1, a2, a3;
            __builtin_memcpy(&a0, &q[j][0], 16);
            __builtin_memcpy(&a1, &q[j][1], 16);
            __builtin_memcpy(&a2, &q[j][2], 16);
            __builtin_memcpy(&a3, &q[j][3], 16);
            h8 v = a0 * F0 + a1 * F1 + a2 * F2 + a3 * F3;
            uint4 ov;
            __builtin_memcpy(&ov, &v, 16);
            int ccs = cc ^ (p & (NCH - 1));
            *(uint4*)&dst[p * C + ccs * 8] = ov;
        }
    };

    f32x4 acc[2][2];
#pragma unroll
    for (int mt = 0; mt < 2; ++mt)
#pragma unroll
        for (int nt = 0; nt < 2; ++nt) acc[mt][nt] = (f32x4){0.f, 0.f, 0.f, 0.f};

    const ushort* bbase[2];
#pragma unroll
    for (int nt = 0; nt < 2; ++nt)
        bbase[nt] = wt + (size_t)(wv * 32 + nt * 16 + n16) * KP + quad * 8;

    auto mfma_run = [&](const ushort* ab, int kc, int s0, int s1) {
#pragma unroll
        for (int s = s0; s < s1; ++s) {
            h8 av[2], bv[2];
            int ch = (s * 4 + quad) ^ xr;
#pragma unroll
            for (int mt = 0; mt < 2; ++mt)
                av[mt] = *(const h8*)(ab + (mt * 16 + n16) * C + ch * 8);
#pragma unroll
            for (int nt = 0; nt < 2; ++nt)
                bv[nt] = *(const h8*)(bbase[nt] + kc * CPW + s * 32);
#pragma unroll
            for (int mt = 0; mt < 2; ++mt)
#pragma unroll
                for (int nt = 0; nt < 2; ++nt)
                    acc[mt][nt] = __builtin_amdgcn_mfma_f32_16x16x32_f16(
                        av[mt], bv[nt], acc[mt][nt], 0, 0, 0);
        }
    };

    {
        uint4 q[HNIT][4];
        uint2 fw[HNIT];
        issue_loads(0, 0, q, fw);
        interp_write(abuf0, 0, q, fw);
        if constexpr (NIT >= 2) {
            issue_loads(0, HNIT, q, fw);
            interp_write(abuf0, HNIT, q, fw);
        }
    }
    __syncthreads();

#pragma unroll 1
    for (int kc = 0; kc < 9; ++kc) {
        const ushort* ab = (kc & 1) ? abuf1 : abuf0;
        ushort* dst = (kc & 1) ? abuf0 : abuf1;
        uint4 q[HNIT][4];
        uint2 fw[HNIT];
        if (kc < 8) issue_loads(kc + 1, 0, q, fw);
        __builtin_amdgcn_s_setprio(1);
        mfma_run(ab, kc, 0, SH);
        __builtin_amdgcn_s_setprio(0);
        if constexpr (NIT >= 2) {
            if (kc < 8) {
                interp_write(dst, 0, q, fw);
                issue_loads(kc + 1, HNIT, q, fw);
            }
            __builtin_amdgcn_s_setprio(1);
            mfma_run(ab, kc, SH, C / 32);
            __builtin_amdgcn_s_setprio(0);
            if (kc < 8) interp_write(dst, HNIT, q, fw);
        } else {
            __builtin_amdgcn_s_setprio(1);
            mfma_run(ab, kc, SH, C / 32);
            __builtin_amdgcn_s_setprio(0);
            if (kc < 8) interp_write(dst, 0, q, fw);
        }
        __syncthreads();
    }

    // ---- epilogue: transpose via LDS; bn stats (fp32) + raw fp16 NHWC out ----
    float* sm = (float*)smem_raw;
    constexpr int SROW = PIX + 1;
#pragma unroll
    for (int mt = 0; mt < 2; ++mt)
#pragma unroll
        for (int nt = 0; nt < 2; ++nt) {
            int o = wv * 32 + nt * 16 + n16;
            int mb = mt * 16 + quad * 4;
#pragma unroll
            for (int r = 0; r < 4; ++r) sm[o * SROW + mb + r] = acc[mt][nt][r];
        }
    __syncthreads();
    {
        // stats: thread = (o, half), 16 px each, fp32-accurate
        int o = tid >> 1, half = tid & 1;
        const float* sp = sm + o * SROW + half * 16;
        float s = 0.f, qq = 0.f;
#pragma unroll
        for (int i = 0; i < 16; i += 4) {
            float4 v = make_float4(sp[i], sp[i + 1], sp[i + 2], sp[i + 3]);
            s += v.x + v.y + v.z + v.w;
            qq += v.x * v.x + v.y * v.y + v.z * v.z + v.w * v.w;
        }
        s += __shfl_down(s, 1, 64);
        qq += __shfl_down(qq, 1, 64);
        if (half == 0) {
            float* pr = praw + (blockIdx.x & 7) * 256;
            atomicAdd(&pr[o], s);
            atomicAdd(&pr[128 + o], qq);
        }
    }
    {
        // NHWC fp16 raw write: thread = (p = tid>>3, cc8 = tid&7), 16 ch
        int p = tid >> 3, cc8 = tid & 7;
        unsigned ov[8];
#pragma unroll
        for (int j = 0; j < 8; ++j) {
            int c = cc8 * 16 + 2 * j;
            ov[j] = f2h2(sm[c * SROW + p], sm[(c + 1) * SROW + p]);
        }
        uint4* dst = (uint4*)(xout + ((size_t)(m0 + p)) * 64 + cc8 * 8);
        dst[0] = uint4{ov[0], ov[1], ov[2], ov[3]};
        dst[1] = uint4{ov[4], ov[5], ov[6], ov[7]};
    }
}

// ---- deformable conv stage-2: PIX=32 (2 rows x 16 cols) -> block-local
// 2x2 maxpool. 8 blocks/CU; same swizzled pipeline. ----
template <int C>
__global__ __launch_bounds__(256, 8) void deform_mfma3p(
    const ushort* __restrict__ xh, const float* __restrict__ dyb,
    const float* __restrict__ dxb, const float* __restrict__ mob,
    const ushort* __restrict__ wt, float* __restrict__ pout,
    float* __restrict__ praw) {
    constexpr int PIX = 32;
    constexpr int NCH = C / 8;
    constexpr int NCC = C / 8;
    constexpr int NIT = PIX * NCC / 256;
    constexpr int HNIT = (NIT >= 2) ? NIT / 2 : 1;
    constexpr int SH = (C / 32) / 2 > 0 ? (C / 32) / 2 : 1;
    constexpr int CPW = C + 8;
    constexpr int KP = ((9 * CPW + 31) / 32) * 32;
    constexpr int ABUF = PIX * C;
    constexpr int LOOPB = 2 * ABUF * 2 + PIX * 9 * 4 + PIX * 9 * 8;
    constexpr int EPIB = 128 * (PIX + 1) * 4;
    constexpr int SMEMB = LOOPB > EPIB ? LOOPB : EPIB;

    __shared__ __align__(16) char smem_raw[SMEMB];
    ushort* abuf0 = (ushort*)smem_raw;
    ushort* abuf1 = abuf0 + ABUF;
    int* tbl = (int*)(abuf0 + 2 * ABUF);
    unsigned* twl = (unsigned*)(smem_raw + 2 * ABUF * 2 + PIX * 9 * 4);

    // XCD-contiguous swizzle, then bid = b*512 + rp*8 + g
    const int bid = (blockIdx.x & 7) * (gridDim.x >> 3) + (blockIdx.x >> 3);
    const int b = bid >> 9;
    const int rp = (bid >> 3) & 63;
    const int g = bid & 7;
    const int tid = threadIdx.x;
    const int lane = tid & 63, wv = tid >> 6;
    const int n16 = lane & 15, quad = lane >> 4;
    const int xr = n16 & (NCH - 1);

    // pixel p in [0,32): row = 2*rp + (p>>4), col = g*16 + (p&15)
    for (int r = tid; r < PIX * 9; r += 256) {
        int p = r & (PIX - 1), k = r >> 5;
        int row = 2 * rp + (p >> 4), col = g * 16 + (p & 15);
        int oi = ((b * 9 + k) << 14) + (row << 7) + col;
        float py = (float)(row + k / 3 - 1) + dyb[oi];
        float px = (float)(col + k % 3 - 1) + dxb[oi];
        float mv = mob[oi];
        float y0f = floorf(py), x0f = floorf(px);
        float wy = py - y0f, wx = px - x0f;
        int y0 = (int)y0f, x0 = (int)x0f;
        int y1 = y0 + 1, x1 = x0 + 1;
        float f00 = (1.f - wy) * (1.f - wx) *
                    (((unsigned)y0 < 128u && (unsigned)x0 < 128u) ? mv : 0.f);
        float f01 = (1.f - wy) * wx *
                    (((unsigned)y0 < 128u && (unsigned)x1 < 128u) ? mv : 0.f);
        float f10 = wy * (1.f - wx) *
                    (((unsigned)y1 < 128u && (unsigned)x0 < 128u) ? mv : 0.f);
        float f11 = wy * wx *
                    (((unsigned)y1 < 128u && (unsigned)x1 < 128u) ? mv : 0.f);
        int cy0 = min(max(y0, 0), 127), cy1 = min(max(y1, 0), 127);
        int cx0 = min(max(x0, 0), 127), cx1 = min(max(x1, 0), 127);
        int base00 = (((b << 14) + (cy0 << 7) + cx0)) * C;
        int flags = ((cy1 != cy0) ? 2 : 0) | ((cx1 != cx0) ? 1 : 0);
        int s = p * 9 + k;
        tbl[s] = base00 | flags;
        twl[2 * s] = f2h2(f00, f01);
        twl[2 * s + 1] = f2h2(f10, f11);
    }
    __syncthreads();

    auto issue_loads = [&](int kc, int it0, uint4 (&q)[HNIT][4],
                           uint2 (&fw)[HNIT]) {
#pragma unroll
        for (int j = 0; j < HNIT; ++j) {
            int e = (it0 + j) * 256 + tid;
            int p = e / NCC, cc = e % NCC;
            int s = p * 9 + kc;
            int ent = tbl[s];
            fw[j] = *(const uint2*)&twl[2 * s];
            int base = ent & ~3;
            int dxo = (ent & 1) ? C : 0;
            int dyo = (ent & 2) ? (C << 7) : 0;
            const ushort* pp = xh + (size_t)base + cc * 8;
            q[j][0] = *(const uint4*)(pp);
            q[j][1] = *(const uint4*)(pp + dxo);
            q[j][2] = *(const uint4*)(pp + dyo);
            q[j][3] = *(const uint4*)(pp + dyo + dxo);
        }
    };
    auto interp_write = [&](ushort* dst, int it0, uint4 (&q)[HNIT][4],
                            uint2 (&fw)[HNIT]) {
#pragma unroll
        for (int j = 0; j < HNIT; ++j) {
            int e = (it0 + j) * 256 + tid;
            int p = e / NCC, cc = e % NCC;
            h2 w01, w23;
            __builtin_memcpy(&w01, &fw[j].x, 4);
            __builtin_memcpy(&w23, &fw[j].y, 4);
            h8 F0 = {w01.x, w01.x, w01.x, w01.x, w01.x, w01.x, w01.x, w01.x};
            h8 F1 = {w01.y, w01.y, w01.y, w01.y, w01.y, w01.y, w01.y, w01.y};
            h8 F2 = {w23.x, w23.x, w23.x, w23.x, w23.x, w23.x, w23.x, w23.x};
            h8 F3 = {w23.y, w23.y, w23.y, w23.y, w23.y, w23.y, w23.y, w23.y};
            h8 a0, a1, a2, a3;
            __builtin_memcpy(&a0, &q[j][0], 16);
            __builtin_memcpy(&a1, &q[j][1], 16);
            __builtin_memcpy(&a2, &q[j][2], 16);
            __builtin_memcpy(&a3, &q[j][3], 16);
            h8 v = a0 * F0 + a1 * F1 + a2 * F2 + a3 * F3;
            uint4 ov;
            __builtin_memcpy(&ov, &v, 16);
            int ccs = cc ^ (p & (NCH - 1));
            *(uint4*)&dst[p * C + ccs * 8] = ov;
        }
    };

    f32x4 acc[2][2];
#pragma unroll
    for (int mt = 0; mt < 2; ++mt)
#pragma unroll
        for (int nt = 0; nt < 2; ++nt) acc[mt][nt] = (f32x4){0.f, 0.f, 0.f, 0.f};

    const ushort* bbase[2];
#pragma unroll
    for (int nt = 0; nt < 2; ++nt)
        bbase[nt] = wt + (size_t)(wv * 32 + nt * 16 + n16) * KP + quad * 8;

    auto mfma_run = [&](const ushort* ab, int kc, int s0, int s1) {
#pragma unroll
        for (int s = s0; s < s1; ++s) {
            h8 av[2], bv[2];
            int ch = (s * 4 + quad) ^ xr;
#pragma unroll
            for (int mt = 0; mt < 2; ++mt)
                av[mt] = *(const h8*)(ab + (mt * 16 + n16) * C + ch * 8);
#pragma unroll
            for (int nt = 0; nt < 2; ++nt)
                bv[nt] = *(const h8*)(bbase[nt] + kc * CPW + s * 32);
#pragma unroll
            for (int mt = 0; mt < 2; ++mt)
#pragma unroll
                for (int nt = 0; nt < 2; ++nt)
                    acc[mt][nt] = __builtin_amdgcn_mfma_f32_16x16x32_f16(
                        av[mt], bv[nt], acc[mt][nt], 0, 0, 0);
        }
    };

    {
        uint4 q[HNIT][4];
        uint2 fw[HNIT];
        issue_loads(0, 0, q, fw);
        interp_write(abuf0, 0, q, fw);
        if constexpr (NIT >= 2) {
            issue_loads(0, HNIT, q, fw);
            interp_write(abuf0, HNIT, q, fw);
        }
    }
    __syncthreads();

#pragma unroll 1
    for (int kc = 0; kc < 9; ++kc) {
        const ushort* ab = (kc & 1) ? abuf1 : abuf0;
        ushort* dst = (kc & 1) ? abuf0 : abuf1;
        uint4 q[HNIT][4];
        uint2 fw[HNIT];
        if (kc < 8) issue_loads(kc + 1, 0, q, fw);
        __builtin_amdgcn_s_setprio(1);
        mfma_run(ab, kc, 0, SH);
        __builtin_amdgcn_s_setprio(0);
        if constexpr (NIT >= 2) {
            if (kc < 8) {
                interp_write(dst, 0, q, fw);
                issue_loads(kc + 1, HNIT, q, fw);
            }
            __builtin_amdgcn_s_setprio(1);
            mfma_run(ab, kc, SH, C / 32);
            __builtin_amdgcn_s_setprio(0);
            if (kc < 8) interp_write(dst, HNIT, q, fw);
        } else {
            __builtin_amdgcn_s_setprio(1);
            mfma_run(ab, kc, SH, C / 32);
            __builtin_amdgcn_s_setprio(0);
            if (kc < 8) interp_write(dst, 0, q, fw);
        }
        __syncthreads();
    }

    // ---- epilogue: stats from full-res tile + block-local 2x2 pool ----
    float* sm = (float*)smem_raw;
    constexpr int SROW = PIX + 1;
#pragma unroll
    for (int mt = 0; mt < 2; ++mt)
#pragma unroll
        for (int nt = 0; nt < 2; ++nt) {
            int o = wv * 32 + nt * 16 + n16;
            int mb = mt * 16 + quad * 4;
#pragma unroll
            for (int r = 0; r < 4; ++r) sm[o * SROW + mb + r] = acc[mt][nt][r];
        }
    __syncthreads();
    {
        int o = tid >> 1, half = tid & 1;
        const float* so = sm + o * SROW;
        const float* sp = so + half * 16;
        float s = 0.f, qq = 0.f;
#pragma unroll
        for (int i = 0; i < 16; i += 4) {
            float4 v = make_float4(sp[i], sp[i + 1], sp[i + 2], sp[i + 3]);
            s += v.x + v.y + v.z + v.w;
            qq += v.x * v.x + v.y * v.y + v.z * v.z + v.w * v.w;
        }
        s += __shfl_down(s, 1, 64);
        qq += __shfl_down(qq, 1, 64);
        if (half == 0) {
            float* pr = praw + (blockIdx.x & 7) * 256;
            atomicAdd(&pr[o], s);
            atomicAdd(&pr[128 + o], qq);
        }
        // pool: rows are px [0,16) and [16,32); pooled cols pc = half*4 + i
        float4 pv;
#pragma unroll
        for (int i = 0; i < 4; ++i) {
            int pc = half * 4 + i;
            float m0v = fmaxf(so[2 * pc], so[2 * pc + 1]);
            float m1v = fmaxf(so[16 + 2 * pc], so[16 + 2 * pc + 1]);
            ((float*)&pv)[i] = fmaxf(m0v, m1v);
        }
        *(float4*)(pout + (((size_t)(b * 128 + o)) << 12) + rp * 64 + g * 8 +
                   half * 4) = pv;
    }
}

// ---- pooled normalize: out = relu((pout - mean) * rstd) ----
__global__ __launch_bounds__(256) void pool_norm(const float* __restrict__ pout,
                                                 const float* __restrict__ praw,
                                                 float* __restrict__ out) {
    __shared__ float lstats[256];
    if (threadIdx.x < 128) {
        int c = threadIdx.x;
        float s = 0.f, q = 0.f;
#pragma unroll
        for (int r = 0; r < 8; ++r) {
            s += praw[r * 256 + c];
            q += praw[r * 256 + 128 + c];
        }
        float mean = s / 65536.f;
        float var = q / 65536.f - mean * mean;
        lstats[c] = mean;
        lstats[128 + c] = rsqrtf(var + 1e-5f);
    }
    __syncthreads();
    int i = blockIdx.x * 256 + threadIdx.x;  // float4 index, total 524288
    int c = (i >> 10) & 127;
    float mean = lstats[c], rstd = lstats[128 + c];
    float4 v = ((const float4*)pout)[i];
    v.x = fmaxf(0.f, (v.x - mean) * rstd);
    v.y = fmaxf(0.f, (v.y - mean) * rstd);
    v.z = fmaxf(0.f, (v.z - mean) * rstd);
    v.w = fmaxf(0.f, (v.w - mean) * rstd);
    ((float4*)out)[i] = v;
}

extern "C" void kernel_launch(void* const* d_in, const int* in_sizes, int n_in,
                              void* d_out, int out_size, void* d_ws,
                              size_t ws_size, hipStream_t stream) {
    (void)in_sizes;
    (void)n_in;
    (void)out_size;
    (void)ws_size;
    const float* x = (const float*)d_in[0];
    const float* w_off1 = (const float*)d_in[1];
    const float* b_off1 = (const float*)d_in[2];
    const float* w_mod1 = (const float*)d_in[3];
    const float* b_mod1 = (const float*)d_in[4];
    const float* w1 = (const float*)d_in[5];
    const float* w_off2 = (const float*)d_in[6];
    const float* b_off2 = (const float*)d_in[7];
    const float* w_mod2 = (const float*)d_in[8];
    const float* b_mod2 = (const float*)d_in[9];
    const float* w2 = (const float*)d_in[10];
    float* out = (float*)d_out;
    float* ws = (float*)d_ws;

    // KP1 = 672 (C=64, CP=72), KP2 = 1248 (C=128, CP=136)
    ushort* Wt1 = (ushort*)ws;                            // 86016 ush = 43008 f
    ushort* Wt2 = (ushort*)(ws + 43008);                  // 159744 ush = 79872 f
    ushort* Wo1 = (ushort*)(ws + 43008 + 79872);          // need 18432 ush
    ushort* Wo2 = (ushort*)(ws + 43008 + 79872 + 16384);  // need 36864 ush
    float* dyb = ws + 172032;
    float* dxb = dyb + 589824;
    float* mob = dxb + 589824;
    float* hbuf = mob + 589824;      // h1 raw fp16 NHWC (4M f); later pout (2M f)
    float* xhf = hbuf + 8388608;     // 2097152 f: x as NHWC fp16
    float* h1hf = xhf + 2097152;     // 4194304 f: h1 normalized NHWC fp16
    float* praw = h1hf + 4194304;    // 2048 (8 replicas x 256)
    ushort* xh = (ushort*)xhf;
    ushort* h1h = (ushort*)h1hf;

    prep_weights<<<1176, 256, 0, stream>>>(w1, w2, w_off1, w_mod1, w_off2,
                                           w_mod2, Wt1, Wt2, Wo1, Wo2);

    // ---- stage 1 ----
    nhwc_cvt<64><<<1024, 256, 0, stream>>>(x, (unsigned*)xh);
    offmod_nhwc<64><<<1024, 256, 0, stream>>>(xh, Wo1, b_off1, b_mod1, dyb, dxb,
                                              mob, praw);
    deform_mfma3<64><<<2048, 256, 0, stream>>>(xh, dyb, dxb, mob, Wt1,
                                               (unsigned*)hbuf, praw);
    bn_apply_ew<<<4096, 256, 0, stream>>>((const unsigned*)hbuf, praw,
                                          (unsigned*)h1h);

    // ---- stage 2 ----
    offmod_nhwc<128><<<1024, 256, 0, stream>>>(h1h, Wo2, b_off2, b_mod2, dyb,
                                               dxb, mob, praw);
    // hbuf (h1 raw) is dead after bn_apply_ew: reuse for pooled raw max
    deform_mfma3p<128><<<2048, 256, 0, stream>>>(h1h, dyb, dxb, mob, Wt2, hbuf,
                                                 praw);
    pool_norm<<<2048, 256, 0, stream>>>(hbuf, praw, out);
}

// Round 7
// 289.705 us; speedup vs baseline: 1.0336x; 1.0336x over previous
//
#include <hip/hip_runtime.h>
#include <math.h>

#define HH 128
#define WW 128
#define HWSZ 16384

typedef __attribute__((ext_vector_type(8))) _Float16 h8;
typedef __attribute__((ext_vector_type(2))) _Float16 h2;
typedef __attribute__((ext_vector_type(4))) float f32x4;
typedef __attribute__((ext_vector_type(2))) float f32x2;
typedef unsigned short ushort;

// fp16 conversion helpers (RNE via scalar cast)
__device__ __forceinline__ ushort f2h(float f) {
    _Float16 h = (_Float16)f;
    ushort u;
    __builtin_memcpy(&u, &h, 2);
    return u;
}
// pack two floats -> packed fp16 dword (lo in [15:0], hi in [31:16])
__device__ __forceinline__ unsigned f2h2(float lo, float hi) {
    h2 r;
    r.x = (_Float16)lo;
    r.y = (_Float16)hi;
    unsigned u;
    __builtin_memcpy(&u, &r, 4);
    return u;
}
// unpack 2 packed fp16 (one dword) to float2
__device__ __forceinline__ f32x2 unpk_h2(unsigned u) {
    h2 h;
    __builtin_memcpy(&h, &u, 4);
    return (f32x2){(float)h.x, (float)h.y};
}

// ---- merged weight prep: wpad1 | wpad2 | woff1 | woff2 in one launch ----
__global__ __launch_bounds__(256) void prep_weights(
    const float* __restrict__ w1, const float* __restrict__ w2,
    const float* __restrict__ w_off1, const float* __restrict__ w_mod1,
    const float* __restrict__ w_off2, const float* __restrict__ w_mod2,
    ushort* __restrict__ Wt1, ushort* __restrict__ Wt2,
    ushort* __restrict__ Wo1, ushort* __restrict__ Wo2) {
    int bid = blockIdx.x, tid = threadIdx.x;
    if (bid < 336) {
        int i = bid * 256 + tid;
        int o = i / 672, kq = i % 672;
        int k = kq / 72, c = kq % 72;
        float v = (k < 9 && c < 64) ? w1[(o * 64 + c) * 9 + k] : 0.f;
        Wt1[i] = f2h(v);
    } else if (bid < 960) {
        int i = (bid - 336) * 256 + tid;
        int o = i / 1248, kq = i % 1248;
        int k = kq / 136, c = kq % 136;
        float v = (k < 9 && c < 128) ? w2[(o * 128 + c) * 9 + k] : 0.f;
        Wt2[i] = f2h(v);
    } else if (bid < 1032) {
        int i = (bid - 960) * 256 + tid;  // < 32*576
        int o = i / 576, kap = i % 576;
        int k = kap / 64, c = kap % 64;
        float v = 0.f;
        if (o < 18) v = w_off1[(o * 64 + c) * 9 + k];
        else if (o < 27) v = w_mod1[((o - 18) * 64 + c) * 9 + k];
        Wo1[i] = f2h(v);
    } else {
        int i = (bid - 1032) * 256 + tid;  // < 32*1152
        int o = i / 1152, kap = i % 1152;
        int k = kap / 128, c = kap % 128;
        float v = 0.f;
        if (o < 18) v = w_off2[(o * 128 + c) * 9 + k];
        else if (o < 27) v = w_mod2[((o - 18) * 128 + c) * 9 + k];
        Wo2[i] = f2h(v);
    }
}

// ---- NCHW fp32 -> NHWC fp16 converter (tiled transpose) ----
template <int C>
__global__ __launch_bounds__(256) void nhwc_cvt(const float* __restrict__ xin,
                                                unsigned* __restrict__ xout) {
    __shared__ float tile[64][C + 1];
    const int m0 = blockIdx.x * 64;
    const int b = m0 >> 14;
    const int hw0 = m0 & 16383;
    const int t = threadIdx.x;
    const int pr = t & 63, cr = t >> 6;
#pragma unroll
    for (int it = 0; it < C / 4; ++it) {
        int c = it * 4 + cr;
        tile[pr][c] = xin[(((size_t)(b * C + c)) << 14) + hw0 + pr];
    }
    __syncthreads();
    constexpr int CH = C / 2;
#pragma unroll
    for (int it = 0; it < 64 * CH / 256; ++it) {
        int slot = it * 256 + t;
        int p = slot / CH, cc = slot % CH;
        xout[(size_t)(m0 + p) * CH + cc] =
            f2h2(tile[p][2 * cc], tile[p][2 * cc + 1]);
    }
}

// ---- elementwise bn finalize + norm/relu on raw NHWC fp16 ----
__global__ __launch_bounds__(256) void bn_apply_ew(
    const unsigned* __restrict__ xin, const float* __restrict__ praw,
    unsigned* __restrict__ xout) {
    __shared__ float lstats[256];
    if (threadIdx.x < 128) {
        int c = threadIdx.x;
        float s = 0.f, q = 0.f;
#pragma unroll
        for (int r = 0; r < 8; ++r) {
            s += praw[r * 256 + c];
            q += praw[r * 256 + 128 + c];
        }
        float mean = s / 65536.f;
        float var = q / 65536.f - mean * mean;
        lstats[c] = mean;
        lstats[128 + c] = rsqrtf(var + 1e-5f);
    }
    __syncthreads();
    int i = blockIdx.x * 256 + threadIdx.x;  // uint4 index (4 dwords = 8 ch)
    uint4 v = ((const uint4*)xin)[i];
    int c0 = ((i * 4) & 63) * 2;  // 64 dwords per pixel (128 ch)
    unsigned ov[4];
    unsigned in[4] = {v.x, v.y, v.z, v.w};
#pragma unroll
    for (int d = 0; d < 4; ++d) {
        int c = c0 + 2 * d;
        f32x2 f = unpk_h2(in[d]);
        float a = fmaxf(0.f, (f.x - lstats[c]) * lstats[128 + c]);
        float b2 = fmaxf(0.f, (f.y - lstats[c + 1]) * lstats[128 + c + 1]);
        ov[d] = f2h2(a, b2);
    }
    ((uint4*)xout)[i] = uint4{ov[0], ov[1], ov[2], ov[3]};
}

// ---- offset/mod conv: NHWC-fp16 direct A-fragment MFMA GEMM ----
// also zeroes the bn praw replicas (blocks 0..7) for the following deform.
template <int C>
__global__ __launch_bounds__(256) void offmod_nhwc(
    const ushort* __restrict__ xh, const ushort* __restrict__ wt,
    const float* __restrict__ b_off, const float* __restrict__ b_mod,
    float* __restrict__ dyb, float* __restrict__ dxb, float* __restrict__ mob,
    float* __restrict__ praw) {
    constexpr int K = C * 9;
    if (blockIdx.x < 8) praw[blockIdx.x * 256 + threadIdx.x] = 0.f;
    const int m0 = blockIdx.x * 64;
    const int b = m0 >> 14;
    const int hw0 = m0 & 16383;
    const int h = hw0 >> 7;
    const int w0 = hw0 & 127;
    const int tid = threadIdx.x;
    const int lane = tid & 63, wv = tid >> 6;
    const int n16 = lane & 15, quad = lane >> 4;
    const int p = wv * 16 + n16;
    const int w = w0 + p;

    int tbase[9];
    bool tval[9];
#pragma unroll
    for (int k = 0; k < 9; ++k) {
        int yy = h + k / 3 - 1, xx = w + k % 3 - 1;
        tval[k] = ((unsigned)yy < 128u) && ((unsigned)xx < 128u);
        int cy = min(max(yy, 0), 127), cx = min(max(xx, 0), 127);
        tbase[k] = ((b << 14) + (cy << 7) + cx) * C + quad * 8;
    }

    f32x4 acc[2];
    acc[0] = (f32x4){0.f, 0.f, 0.f, 0.f};
    acc[1] = (f32x4){0.f, 0.f, 0.f, 0.f};

    const ushort* b0p = wt + (size_t)n16 * K + quad * 8;
    const ushort* b1p = wt + (size_t)(16 + n16) * K + quad * 8;

#pragma unroll
    for (int s = 0; s < K / 32; ++s) {
        const int k = (s * 32) / C;
        const int c0 = (s * 32) % C;
        h8 a = {0, 0, 0, 0, 0, 0, 0, 0};
        if (tval[k]) a = *(const h8*)(xh + (size_t)tbase[k] + c0);
        const h8 bv0 = *(const h8*)(b0p + s * 32);
        const h8 bv1 = *(const h8*)(b1p + s * 32);
        acc[0] = __builtin_amdgcn_mfma_f32_16x16x32_f16(a, bv0, acc[0], 0, 0, 0);
        acc[1] = __builtin_amdgcn_mfma_f32_16x16x32_f16(a, bv1, acc[1], 0, 0, 0);
    }

    __shared__ float sm[32 * 65];
#pragma unroll
    for (int nt = 0; nt < 2; ++nt) {
        int n = nt * 16 + n16;
        int pb = wv * 16 + quad * 4;
#pragma unroll
        for (int r = 0; r < 4; ++r) sm[n * 65 + pb + r] = acc[nt][r];
    }
    __syncthreads();
    {
        int n = tid >> 3, i8 = tid & 7;
        if (n < 27) {
            const float* sp = sm + n * 65 + i8 * 8;
            int px = hw0 + i8 * 8;
            if (n < 18) {
                int k = n >> 1;
                float bias = b_off[n];
                float* dst =
                    ((n & 1) ? dxb : dyb) + (((size_t)(b * 9 + k)) << 14) + px;
#pragma unroll
                for (int j = 0; j < 8; j += 4) {
                    float4 v = make_float4(sp[j] + bias, sp[j + 1] + bias,
                                           sp[j + 2] + bias, sp[j + 3] + bias);
                    *(float4*)(dst + j) = v;
                }
            } else {
                float bias = b_mod[n - 18];
                float* dst = mob + (((size_t)(b * 9 + (n - 18))) << 14) + px;
#pragma unroll
                for (int j = 0; j < 8; j += 4) {
                    float4 v;
                    v.x = 2.f / (1.f + expf(-(sp[j] + bias)));
                    v.y = 2.f / (1.f + expf(-(sp[j + 1] + bias)));
                    v.z = 2.f / (1.f + expf(-(sp[j + 2] + bias)));
                    v.w = 2.f / (1.f + expf(-(sp[j + 3] + bias)));
                    *(float4*)(dst + j) = v;
                }
            }
        }
    }
}

// ---- deformable conv v3 (stage 1): PIX=32, 8 blocks/CU target,
// bounds(256,6) so the allocator is NOT forced below its natural ~52-64 VGPR
// (R6's (256,8) caused a pathological 32-VGPR spill build). ----
template <int C>
__global__ __launch_bounds__(256, 6) void deform_mfma3(
    const ushort* __restrict__ xh, const float* __restrict__ dyb,
    const float* __restrict__ dxb, const float* __restrict__ mob,
    const ushort* __restrict__ wt, unsigned* __restrict__ xout,
    float* __restrict__ praw) {
    constexpr int PIX = 32;
    constexpr int NCH = C / 8;   // 16B chunks per row
    constexpr int NCC = C / 8;
    constexpr int NIT = PIX * NCC / 256;
    constexpr int HNIT = (NIT >= 2) ? NIT / 2 : 1;
    constexpr int SH = (C / 32) / 2 > 0 ? (C / 32) / 2 : 1;
    constexpr int CPW = C + 8;
    constexpr int KP = ((9 * CPW + 31) / 32) * 32;
    constexpr int ABUF = PIX * C;  // ushorts, no pad (XOR swizzle instead)
    constexpr int LOOPB = 2 * ABUF * 2 + PIX * 9 * 4 + PIX * 9 * 8;
    constexpr int EPIB = 128 * (PIX + 1) * 4;
    constexpr int SMEMB = LOOPB > EPIB ? LOOPB : EPIB;

    __shared__ __align__(16) char smem_raw[SMEMB];
    ushort* abuf0 = (ushort*)smem_raw;
    ushort* abuf1 = abuf0 + ABUF;
    int* tbl = (int*)(abuf0 + 2 * ABUF);
    unsigned* twl = (unsigned*)(smem_raw + 2 * ABUF * 2 + PIX * 9 * 4);

    // XCD-contiguous swizzle: each XCD owns a contiguous 1/8 of the image.
    const int bid = (blockIdx.x & 7) * (gridDim.x >> 3) + (blockIdx.x >> 3);
    const int m0 = bid * PIX;
    const int b = m0 >> 14;
    const int hw0 = m0 & 16383;
    const int h = hw0 >> 7, w0 = hw0 & 127;
    const int tid = threadIdx.x;
    const int lane = tid & 63, wv = tid >> 6;
    const int n16 = lane & 15, quad = lane >> 4;
    const int xr = n16 & (NCH - 1);

    for (int r = tid; r < PIX * 9; r += 256) {
        int p = r & (PIX - 1), k = r >> 5;
        int oi = ((b * 9 + k) << 14) + hw0 + p;
        float py = (float)(h + k / 3 - 1) + dyb[oi];
        float px = (float)(w0 + p + k % 3 - 1) + dxb[oi];
        float mv = mob[oi];
        float y0f = floorf(py), x0f = floorf(px);
        float wy = py - y0f, wx = px - x0f;
        int y0 = (int)y0f, x0 = (int)x0f;
        int y1 = y0 + 1, x1 = x0 + 1;
        float f00 = (1.f - wy) * (1.f - wx) *
                    (((unsigned)y0 < 128u && (unsigned)x0 < 128u) ? mv : 0.f);
        float f01 = (1.f - wy) * wx *
                    (((unsigned)y0 < 128u && (unsigned)x1 < 128u) ? mv : 0.f);
        float f10 = wy * (1.f - wx) *
                    (((unsigned)y1 < 128u && (unsigned)x0 < 128u) ? mv : 0.f);
        float f11 = wy * wx *
                    (((unsigned)y1 < 128u && (unsigned)x1 < 128u) ? mv : 0.f);
        int cy0 = min(max(y0, 0), 127), cy1 = min(max(y1, 0), 127);
        int cx0 = min(max(x0, 0), 127), cx1 = min(max(x1, 0), 127);
        int base00 = (((b << 14) + (cy0 << 7) + cx0)) * C;
        int flags = ((cy1 != cy0) ? 2 : 0) | ((cx1 != cx0) ? 1 : 0);
        int s = p * 9 + k;
        tbl[s] = base00 | flags;
        twl[2 * s] = f2h2(f00, f01);
        twl[2 * s + 1] = f2h2(f10, f11);
    }
    __syncthreads();

    auto issue_loads = [&](int kc, int it0, uint4 (&q)[HNIT][4],
                           uint2 (&fw)[HNIT]) {
#pragma unroll
        for (int j = 0; j < HNIT; ++j) {
            int e = (it0 + j) * 256 + tid;
            int p = e / NCC, cc = e % NCC;
            int s = p * 9 + kc;
            int ent = tbl[s];
            fw[j] = *(const uint2*)&twl[2 * s];
            int base = ent & ~3;
            int dxo = (ent & 1) ? C : 0;
            int dyo = (ent & 2) ? (C << 7) : 0;
            const ushort* pp = xh + (size_t)base + cc * 8;
            q[j][0] = *(const uint4*)(pp);
            q[j][1] = *(const uint4*)(pp + dxo);
            q[j][2] = *(const uint4*)(pp + dyo);
            q[j][3] = *(const uint4*)(pp + dyo + dxo);
        }
    };
    auto interp_write = [&](ushort* dst, int it0, uint4 (&q)[HNIT][4],
                            uint2 (&fw)[HNIT]) {
#pragma unroll
        for (int j = 0; j < HNIT; ++j) {
            int e = (it0 + j) * 256 + tid;
            int p = e / NCC, cc = e % NCC;
            h2 w01, w23;
            __builtin_memcpy(&w01, &fw[j].x, 4);
            __builtin_memcpy(&w23, &fw[j].y, 4);
            h8 F0 = {w01.x, w01.x, w01.x, w01.x, w01.x, w01.x, w01.x, w01.x};
            h8 F1 = {w01.y, w01.y, w01.y, w01.y, w01.y, w01.y, w01.y, w01.y};
            h8 F2 = {w23.x, w23.x, w23.x, w23.x, w23.x, w23.x, w23.x, w23.x};
            h8 F3 = {w23.y, w23.y, w23.y, w23.y, w23.y, w23.y, w23.y, w23.y};
            h8 a0, a1, a2, a3;
            __builtin_memcpy(&a0, &q[j][0], 16);
            __builtin_memcpy(&a1, &q[j][1], 16);
            __builtin_memcpy(&a2, &q[j][2], 16);
            __builtin_memcpy(&a3, &q[j][3], 16);
            h8 v = a0 * F0 + a1 * F1 + a2 * F2 + a3 * F3;
            uint4 ov;
            __builtin_memcpy(&ov, &v, 16);
            int ccs = cc ^ (p & (NCH - 1));
            *(uint4*)&dst[p * C + ccs * 8] = ov;
        }
    };

    f32x4 acc[2][2];
#pragma unroll
    for (int mt = 0; mt < 2; ++mt)
#pragma unroll
        for (int nt = 0; nt < 2; ++nt) acc[mt][nt] = (f32x4){0.f, 0.f, 0.f, 0.f};

    const ushort* bbase[2];
#pragma unroll
    for (int nt = 0; nt < 2; ++nt)
        bbase[nt] = wt + (size_t)(wv * 32 + nt * 16 + n16) * KP + quad * 8;

    auto mfma_run = [&](const ushort* ab, int kc, int s0, int s1) {
#pragma unroll
        for (int s = s0; s < s1; ++s) {
            h8 av[2], bv[2];
            int ch = (s * 4 + quad) ^ xr;
#pragma unroll
            for (int mt = 0; mt < 2; ++mt)
                av[mt] = *(const h8*)(ab + (mt * 16 + n16) * C + ch * 8);
#pragma unroll
            for (int nt = 0; nt < 2; ++nt)
                bv[nt] = *(const h8*)(bbase[nt] + kc * CPW + s * 32);
#pragma unroll
            for (int mt = 0; mt < 2; ++mt)
#pragma unroll
                for (int nt = 0; nt < 2; ++nt)
                    acc[mt][nt] = __builtin_amdgcn_mfma_f32_16x16x32_f16(
                        av[mt], bv[nt], acc[mt][nt], 0, 0, 0);
        }
    };

    {
        uint4 q[HNIT][4];
        uint2 fw[HNIT];
        issue_loads(0, 0, q, fw);
        interp_write(abuf0, 0, q, fw);
        if constexpr (NIT >= 2) {
            issue_loads(0, HNIT, q, fw);
            interp_write(abuf0, HNIT, q, fw);
        }
    }
    __syncthreads();

#pragma unroll 1
    for (int kc = 0; kc < 9; ++kc) {
        const ushort* ab = (kc & 1) ? abuf1 : abuf0;
        ushort* dst = (kc & 1) ? abuf0 : abuf1;
        uint4 q[HNIT][4];
        uint2 fw[HNIT];
        if (kc < 8) issue_loads(kc + 1, 0, q, fw);
        __builtin_amdgcn_s_setprio(1);
        mfma_run(ab, kc, 0, SH);
        __builtin_amdgcn_s_setprio(0);
        if constexpr (NIT >= 2) {
            if (kc < 8) {
                interp_write(dst, 0, q, fw);
                issue_loads(kc + 1, HNIT, q, fw);
            }
            __builtin_amdgcn_s_setprio(1);
            mfma_run(ab, kc, SH, C / 32);
            __builtin_amdgcn_s_setprio(0);
            if (kc < 8) interp_write(dst, HNIT, q, fw);
        } else {
            __builtin_amdgcn_s_setprio(1);
            mfma_run(ab, kc, SH, C / 32);
            __builtin_amdgcn_s_setprio(0);
            if (kc < 8) interp_write(dst, 0, q, fw);
        }
        __syncthreads();
    }

    // ---- epilogue: transpose via LDS; bn stats (fp32) + raw fp16 NHWC out ----
    float* sm = (float*)smem_raw;
    constexpr int SROW = PIX + 1;
#pragma unroll
    for (int mt = 0; mt < 2; ++mt)
#pragma unroll
        for (int nt = 0; nt < 2; ++nt) {
            int o = wv * 32 + nt * 16 + n16;
            int mb = mt * 16 + quad * 4;
#pragma unroll
            for (int r = 0; r < 4; ++r) sm[o * SROW + mb + r] = acc[mt][nt][r];
        }
    __syncthreads();
    {
        // stats: thread = (o, half), 16 px each, fp32-accurate
        int o = tid >> 1, half = tid & 1;
        const float* sp = sm + o * SROW + half * 16;
        float s = 0.f, qq = 0.f;
#pragma unroll
        for (int i = 0; i < 16; i += 4) {
            float4 v = make_float4(sp[i], sp[i + 1], sp[i + 2], sp[i + 3]);
            s += v.x + v.y + v.z + v.w;
            qq += v.x * v.x + v.y * v.y + v.z * v.z + v.w * v.w;
        }
        s += __shfl_down(s, 1, 64);
        qq += __shfl_down(qq, 1, 64);
        if (half == 0) {
            float* pr = praw + (blockIdx.x & 7) * 256;
            atomicAdd(&pr[o], s);
            atomicAdd(&pr[128 + o], qq);
        }
    }
    {
        // NHWC fp16 raw write: thread = (p = tid>>3, cc8 = tid&7), 16 ch
        int p = tid >> 3, cc8 = tid & 7;
        unsigned ov[8];
#pragma unroll
        for (int j = 0; j < 8; ++j) {
            int c = cc8 * 16 + 2 * j;
            ov[j] = f2h2(sm[c * SROW + p], sm[(c + 1) * SROW + p]);
        }
        uint4* dst = (uint4*)(xout + ((size_t)(m0 + p)) * 64 + cc8 * 8);
        dst[0] = uint4{ov[0], ov[1], ov[2], ov[3]};
        dst[1] = uint4{ov[4], ov[5], ov[6], ov[7]};
    }
}

// ---- deformable conv stage-2: PIX=32 (2 rows x 16 cols) -> register-only
// epilogue (bn stats via shfl_xor, 2x2 pool lane-local). 8 blocks/CU. ----
template <int C>
__global__ __launch_bounds__(256, 6) void deform_mfma3p(
    const ushort* __restrict__ xh, const float* __restrict__ dyb,
    const float* __restrict__ dxb, const float* __restrict__ mob,
    const ushort* __restrict__ wt, float* __restrict__ pout,
    float* __restrict__ praw) {
    constexpr int PIX = 32;
    constexpr int NCH = C / 8;
    constexpr int NCC = C / 8;
    constexpr int NIT = PIX * NCC / 256;
    constexpr int HNIT = (NIT >= 2) ? NIT / 2 : 1;
    constexpr int SH = (C / 32) / 2 > 0 ? (C / 32) / 2 : 1;
    constexpr int CPW = C + 8;
    constexpr int KP = ((9 * CPW + 31) / 32) * 32;
    constexpr int ABUF = PIX * C;
    constexpr int SMEMB = 2 * ABUF * 2 + PIX * 9 * 4 + PIX * 9 * 8;

    __shared__ __align__(16) char smem_raw[SMEMB];
    ushort* abuf0 = (ushort*)smem_raw;
    ushort* abuf1 = abuf0 + ABUF;
    int* tbl = (int*)(abuf0 + 2 * ABUF);
    unsigned* twl = (unsigned*)(smem_raw + 2 * ABUF * 2 + PIX * 9 * 4);

    // XCD-contiguous swizzle, then bid = b*512 + rp*8 + g
    const int bid = (blockIdx.x & 7) * (gridDim.x >> 3) + (blockIdx.x >> 3);
    const int b = bid >> 9;
    const int rp = (bid >> 3) & 63;
    const int g = bid & 7;
    const int tid = threadIdx.x;
    const int lane = tid & 63, wv = tid >> 6;
    const int n16 = lane & 15, quad = lane >> 4;
    const int xr = n16 & (NCH - 1);

    // pixel p in [0,32): row = 2*rp + (p>>4), col = g*16 + (p&15)
    for (int r = tid; r < PIX * 9; r += 256) {
        int p = r & (PIX - 1), k = r >> 5;
        int row = 2 * rp + (p >> 4), col = g * 16 + (p & 15);
        int oi = ((b * 9 + k) << 14) + (row << 7) + col;
        float py = (float)(row + k / 3 - 1) + dyb[oi];
        float px = (float)(col + k % 3 - 1) + dxb[oi];
        float mv = mob[oi];
        float y0f = floorf(py), x0f = floorf(px);
        float wy = py - y0f, wx = px - x0f;
        int y0 = (int)y0f, x0 = (int)x0f;
        int y1 = y0 + 1, x1 = x0 + 1;
        float f00 = (1.f - wy) * (1.f - wx) *
                    (((unsigned)y0 < 128u && (unsigned)x0 < 128u) ? mv : 0.f);
        float f01 = (1.f - wy) * wx *
                    (((unsigned)y0 < 128u && (unsigned)x1 < 128u) ? mv : 0.f);
        float f10 = wy * (1.f - wx) *
                    (((unsigned)y1 < 128u && (unsigned)x0 < 128u) ? mv : 0.f);
        float f11 = wy * wx *
                    (((unsigned)y1 < 128u && (unsigned)x1 < 128u) ? mv : 0.f);
        int cy0 = min(max(y0, 0), 127), cy1 = min(max(y1, 0), 127);
        int cx0 = min(max(x0, 0), 127), cx1 = min(max(x1, 0), 127);
        int base00 = (((b << 14) + (cy0 << 7) + cx0)) * C;
        int flags = ((cy1 != cy0) ? 2 : 0) | ((cx1 != cx0) ? 1 : 0);
        int s = p * 9 + k;
        tbl[s] = base00 | flags;
        twl[2 * s] = f2h2(f00, f01);
        twl[2 * s + 1] = f2h2(f10, f11);
    }
    __syncthreads();

    auto issue_loads = [&](int kc, int it0, uint4 (&q)[HNIT][4],
                           uint2 (&fw)[HNIT]) {
#pragma unroll
        for (int j = 0; j < HNIT; ++j) {
            int e = (it0 + j) * 256 + tid;
            int p = e / NCC, cc = e % NCC;
            int s = p * 9 + kc;
            int ent = tbl[s];
            fw[j] = *(const uint2*)&twl[2 * s];
            int base = ent & ~3;
            int dxo = (ent & 1) ? C : 0;
            int dyo = (ent & 2) ? (C << 7) : 0;
            const ushort* pp = xh + (size_t)base + cc * 8;
            q[j][0] = *(const uint4*)(pp);
            q[j][1] = *(const uint4*)(pp + dxo);
            q[j][2] = *(const uint4*)(pp + dyo);
            q[j][3] = *(const uint4*)(pp + dyo + dxo);
        }
    };
    auto interp_write = [&](ushort* dst, int it0, uint4 (&q)[HNIT][4],
                            uint2 (&fw)[HNIT]) {
#pragma unroll
        for (int j = 0; j < HNIT; ++j) {
            int e = (it0 + j) * 256 + tid;
            int p = e / NCC, cc = e % NCC;
            h2 w01, w23;
            __builtin_memcpy(&w01, &fw[j].x, 4);
            __builtin_memcpy(&w23, &fw[j].y, 4);
            h8 F0 = {w01.x, w01.x, w01.x, w01.x, w01.x, w01.x, w01.x, w01.x};
            h8 F1 = {w01.y, w01.y, w01.y, w01.y, w01.y, w01.y, w01.y, w01.y};
            h8 F2 = {w23.x, w23.x, w23.x, w23.x, w23.x, w23.x, w23.x, w23.x};
            h8 F3 = {w23.y, w23.y, w23.y, w23.y, w23.y, w23.y, w23.y, w23.y};
            h8 a0, a1, a2, a3;
            __builtin_memcpy(&a0, &q[j][0], 16);
            __builtin_memcpy(&a1, &q[j][1], 16);
            __builtin_memcpy(&a2, &q[j][2], 16);
            __builtin_memcpy(&a3, &q[j][3], 16);
            h8 v = a0 * F0 + a1 * F1 + a2 * F2 + a3 * F3;
            uint4 ov;
            __builtin_memcpy(&ov, &v, 16);
            int ccs = cc ^ (p & (NCH - 1));
            *(uint4*)&dst[p * C + ccs * 8] = ov;
        }
    };

    f32x4 acc[2][2];
#pragma unroll
    for (int mt = 0; mt < 2; ++mt)
#pragma unroll
        for (int nt = 0; nt < 2; ++nt) acc[mt][nt] = (f32x4){0.f, 0.f, 0.f, 0.f};

    const ushort* bbase[2];
#pragma unroll
    for (int nt = 0; nt < 2; ++nt)
        bbase[nt] = wt + (size_t)(wv * 32 + nt * 16 + n16) * KP + quad * 8;

    auto mfma_run = [&](const ushort* ab, int kc, int s0, int s1) {
#pragma unroll
        for (int s = s0; s < s1; ++s) {
            h8 av[2], bv[2];
            int ch = (s * 4 + quad) ^ xr;
#pragma unroll
            for (int mt = 0; mt < 2; ++mt)
                av[mt] = *(const h8*)(ab + (mt * 16 + n16) * C + ch * 8);
#pragma unroll
            for (int nt = 0; nt < 2; ++nt)
                bv[nt] = *(const h8*)(bbase[nt] + kc * CPW + s * 32);
#pragma unroll
            for (int mt = 0; mt < 2; ++mt)
#pragma unroll
                for (int nt = 0; nt < 2; ++nt)
                    acc[mt][nt] = __builtin_amdgcn_mfma_f32_16x16x32_f16(
                        av[mt], bv[nt], acc[mt][nt], 0, 0, 0);
        }
    };

    {
        uint4 q[HNIT][4];
        uint2 fw[HNIT];
        issue_loads(0, 0, q, fw);
        interp_write(abuf0, 0, q, fw);
        if constexpr (NIT >= 2) {
            issue_loads(0, HNIT, q, fw);
            interp_write(abuf0, HNIT, q, fw);
        }
    }
    __syncthreads();

#pragma unroll 1
    for (int kc = 0; kc < 9; ++kc) {
        const ushort* ab = (kc & 1) ? abuf1 : abuf0;
        ushort* dst = (kc & 1) ? abuf0 : abuf1;
        uint4 q[HNIT][4];
        uint2 fw[HNIT];
        if (kc < 8) issue_loads(kc + 1, 0, q, fw);
        __builtin_amdgcn_s_setprio(1);
        mfma_run(ab, kc, 0, SH);
        __builtin_amdgcn_s_setprio(0);
        if constexpr (NIT >= 2) {
            if (kc < 8) {
                interp_write(dst, 0, q, fw);
                issue_loads(kc + 1, HNIT, q, fw);
            }
            __builtin_amdgcn_s_setprio(1);
            mfma_run(ab, kc, SH, C / 32);
            __builtin_amdgcn_s_setprio(0);
            if (kc < 8) interp_write(dst, HNIT, q, fw);
        } else {
            __builtin_amdgcn_s_setprio(1);
            mfma_run(ab, kc, SH, C / 32);
            __builtin_amdgcn_s_setprio(0);
            if (kc < 8) interp_write(dst, 0, q, fw);
        }
        __syncthreads();
    }

    // ---- epilogue: register-only bn stats + register 2x2 pool ----
    // acc[mt][nt][r]: o = wv*32 + nt*16 + n16 ; px = mt*16 + quad*4 + r
    // (px>>4 = row within pair, px&15 = col)
#pragma unroll
    for (int nt = 0; nt < 2; ++nt) {
        int o = wv * 32 + nt * 16 + n16;
        float s = 0.f, qq = 0.f;
#pragma unroll
        for (int mt = 0; mt < 2; ++mt)
#pragma unroll
            for (int r = 0; r < 4; ++r) {
                float v = acc[mt][nt][r];
                s += v;
                qq += v * v;
            }
        s += __shfl_xor(s, 16, 64);
        s += __shfl_xor(s, 32, 64);
        qq += __shfl_xor(qq, 16, 64);
        qq += __shfl_xor(qq, 32, 64);
        if (quad == 0) {
            float* pr = praw + (blockIdx.x & 7) * 256;
            atomicAdd(&pr[o], s);
            atomicAdd(&pr[128 + o], qq);
        }
        // 2x2 pool: rows = mt0/mt1; col pairs within lane (r pairs).
        // pooled col pc = quad*2 + rp2
        float* po = pout + (((size_t)(b * 128 + o)) << 12) + rp * 64 + g * 8;
#pragma unroll
        for (int rp2 = 0; rp2 < 2; ++rp2) {
            float m =
                fmaxf(fmaxf(acc[0][nt][2 * rp2], acc[0][nt][2 * rp2 + 1]),
                      fmaxf(acc[1][nt][2 * rp2], acc[1][nt][2 * rp2 + 1]));
            po[quad * 2 + rp2] = m;
        }
    }
}

// ---- pooled normalize: out = relu((pout - mean) * rstd) ----
__global__ __launch_bounds__(256) void pool_norm(const float* __restrict__ pout,
                                                 const float* __restrict__ praw,
                                                 float* __restrict__ out) {
    __shared__ float lstats[256];
    if (threadIdx.x < 128) {
        int c = threadIdx.x;
        float s = 0.f, q = 0.f;
#pragma unroll
        for (int r = 0; r < 8; ++r) {
            s += praw[r * 256 + c];
            q += praw[r * 256 + 128 + c];
        }
        float mean = s / 65536.f;
        float var = q / 65536.f - mean * mean;
        lstats[c] = mean;
        lstats[128 + c] = rsqrtf(var + 1e-5f);
    }
    __syncthreads();
    int i = blockIdx.x * 256 + threadIdx.x;  // float4 index, total 524288
    int c = (i >> 10) & 127;
    float mean = lstats[c], rstd = lstats[128 + c];
    float4 v = ((const float4*)pout)[i];
    v.x = fmaxf(0.f, (v.x - mean) * rstd);
    v.y = fmaxf(0.f, (v.y - mean) * rstd);
    v.z = fmaxf(0.f, (v.z - mean) * rstd);
    v.w = fmaxf(0.f, (v.w - mean) * rstd);
    ((float4*)out)[i] = v;
}

extern "C" void kernel_launch(void* const* d_in, const int* in_sizes, int n_in,
                              void* d_out, int out_size, void* d_ws,
                              size_t ws_size, hipStream_t stream) {
    (void)in_sizes;
    (void)n_in;
    (void)out_size;
    (void)ws_size;
    const float* x = (const float*)d_in[0];
    const float* w_off1 = (const float*)d_in[1];
    const float* b_off1 = (const float*)d_in[2];
    const float* w_mod1 = (const float*)d_in[3];
    const float* b_mod1 = (const float*)d_in[4];
    const float* w1 = (const float*)d_in[5];
    const float* w_off2 = (const float*)d_in[6];
    const float* b_off2 = (const float*)d_in[7];
    const float* w_mod2 = (const float*)d_in[8];
    const float* b_mod2 = (const float*)d_in[9];
    const float* w2 = (const float*)d_in[10];
    float* out = (float*)d_out;
    float* ws = (float*)d_ws;

    // KP1 = 672 (C=64, CP=72), KP2 = 1248 (C=128, CP=136)
    ushort* Wt1 = (ushort*)ws;                            // 86016 ush = 43008 f
    ushort* Wt2 = (ushort*)(ws + 43008);                  // 159744 ush = 79872 f
    ushort* Wo1 = (ushort*)(ws + 43008 + 79872);          // need 18432 ush
    ushort* Wo2 = (ushort*)(ws + 43008 + 79872 + 16384);  // need 36864 ush
    float* dyb = ws + 172032;
    float* dxb = dyb + 589824;
    float* mob = dxb + 589824;
    float* hbuf = mob + 589824;      // h1 raw fp16 NHWC (4M f); later pout (2M f)
    float* xhf = hbuf + 8388608;     // 2097152 f: x as NHWC fp16
    float* h1hf = xhf + 2097152;     // 4194304 f: h1 normalized NHWC fp16
    float* praw = h1hf + 4194304;    // 2048 (8 replicas x 256)
    ushort* xh = (ushort*)xhf;
    ushort* h1h = (ushort*)h1hf;

    prep_weights<<<1176, 256, 0, stream>>>(w1, w2, w_off1, w_mod1, w_off2,
                                           w_mod2, Wt1, Wt2, Wo1, Wo2);

    // ---- stage 1 ----
    nhwc_cvt<64><<<1024, 256, 0, stream>>>(x, (unsigned*)xh);
    offmod_nhwc<64><<<1024, 256, 0, stream>>>(xh, Wo1, b_off1, b_mod1, dyb, dxb,
                                              mob, praw);
    deform_mfma3<64><<<2048, 256, 0, stream>>>(xh, dyb, dxb, mob, Wt1,
                                               (unsigned*)hbuf, praw);
    bn_apply_ew<<<4096, 256, 0, stream>>>((const unsigned*)hbuf, praw,
                                          (unsigned*)h1h);

    // ---- stage 2 ----
    offmod_nhwc<128><<<1024, 256, 0, stream>>>(h1h, Wo2, b_off2, b_mod2, dyb,
                                               dxb, mob, praw);
    // hbuf (h1 raw) is dead after bn_apply_ew: reuse for pooled raw max
    deform_mfma3p<128><<<2048, 256, 0, stream>>>(h1h, dyb, dxb, mob, Wt2, hbuf,
                                                 praw);
    pool_norm<<<2048, 256, 0, stream>>>(hbuf, praw, out);
}

// Round 8
// 252.829 us; speedup vs baseline: 1.1844x; 1.1459x over previous
//
#include <hip/hip_runtime.h>
#include <math.h>

#define HH 128
#define WW 128
#define HWSZ 16384

typedef __attribute__((ext_vector_type(8))) _Float16 h8;
typedef __attribute__((ext_vector_type(2))) _Float16 h2;
typedef __attribute__((ext_vector_type(4))) float f32x4;
typedef __attribute__((ext_vector_type(2))) float f32x2;
typedef unsigned short ushort;

// fp16 conversion helpers (RNE via scalar cast)
__device__ __forceinline__ ushort f2h(float f) {
    _Float16 h = (_Float16)f;
    ushort u;
    __builtin_memcpy(&u, &h, 2);
    return u;
}
// pack two floats -> packed fp16 dword (lo in [15:0], hi in [31:16])
__device__ __forceinline__ unsigned f2h2(float lo, float hi) {
    h2 r;
    r.x = (_Float16)lo;
    r.y = (_Float16)hi;
    unsigned u;
    __builtin_memcpy(&u, &r, 4);
    return u;
}
// unpack 2 packed fp16 (one dword) to float2
__device__ __forceinline__ f32x2 unpk_h2(unsigned u) {
    h2 h;
    __builtin_memcpy(&h, &u, 4);
    return (f32x2){(float)h.x, (float)h.y};
}

// ---- merged weight prep: wpad1 | wpad2 | woff1 | woff2 in one launch ----
__global__ __launch_bounds__(256) void prep_weights(
    const float* __restrict__ w1, const float* __restrict__ w2,
    const float* __restrict__ w_off1, const float* __restrict__ w_mod1,
    const float* __restrict__ w_off2, const float* __restrict__ w_mod2,
    ushort* __restrict__ Wt1, ushort* __restrict__ Wt2,
    ushort* __restrict__ Wo1, ushort* __restrict__ Wo2) {
    int bid = blockIdx.x, tid = threadIdx.x;
    if (bid < 336) {
        int i = bid * 256 + tid;
        int o = i / 672, kq = i % 672;
        int k = kq / 72, c = kq % 72;
        float v = (k < 9 && c < 64) ? w1[(o * 64 + c) * 9 + k] : 0.f;
        Wt1[i] = f2h(v);
    } else if (bid < 960) {
        int i = (bid - 336) * 256 + tid;
        int o = i / 1248, kq = i % 1248;
        int k = kq / 136, c = kq % 136;
        float v = (k < 9 && c < 128) ? w2[(o * 128 + c) * 9 + k] : 0.f;
        Wt2[i] = f2h(v);
    } else if (bid < 1032) {
        int i = (bid - 960) * 256 + tid;  // < 32*576
        int o = i / 576, kap = i % 576;
        int k = kap / 64, c = kap % 64;
        float v = 0.f;
        if (o < 18) v = w_off1[(o * 64 + c) * 9 + k];
        else if (o < 27) v = w_mod1[((o - 18) * 64 + c) * 9 + k];
        Wo1[i] = f2h(v);
    } else {
        int i = (bid - 1032) * 256 + tid;  // < 32*1152
        int o = i / 1152, kap = i % 1152;
        int k = kap / 128, c = kap % 128;
        float v = 0.f;
        if (o < 18) v = w_off2[(o * 128 + c) * 9 + k];
        else if (o < 27) v = w_mod2[((o - 18) * 128 + c) * 9 + k];
        Wo2[i] = f2h(v);
    }
}

// ---- NCHW fp32 -> NHWC fp16 converter (tiled transpose) ----
template <int C>
__global__ __launch_bounds__(256) void nhwc_cvt(const float* __restrict__ xin,
                                                unsigned* __restrict__ xout) {
    __shared__ float tile[64][C + 1];
    const int m0 = blockIdx.x * 64;
    const int b = m0 >> 14;
    const int hw0 = m0 & 16383;
    const int t = threadIdx.x;
    const int pr = t & 63, cr = t >> 6;
#pragma unroll
    for (int it = 0; it < C / 4; ++it) {
        int c = it * 4 + cr;
        tile[pr][c] = xin[(((size_t)(b * C + c)) << 14) + hw0 + pr];
    }
    __syncthreads();
    constexpr int CH = C / 2;
#pragma unroll
    for (int it = 0; it < 64 * CH / 256; ++it) {
        int slot = it * 256 + t;
        int p = slot / CH, cc = slot % CH;
        xout[(size_t)(m0 + p) * CH + cc] =
            f2h2(tile[p][2 * cc], tile[p][2 * cc + 1]);
    }
}

// ---- elementwise bn finalize + norm/relu on raw NHWC fp16 ----
__global__ __launch_bounds__(256) void bn_apply_ew(
    const unsigned* __restrict__ xin, const float* __restrict__ praw,
    unsigned* __restrict__ xout) {
    __shared__ float lstats[256];
    if (threadIdx.x < 128) {
        int c = threadIdx.x;
        float s = 0.f, q = 0.f;
#pragma unroll
        for (int r = 0; r < 8; ++r) {
            s += praw[r * 256 + c];
            q += praw[r * 256 + 128 + c];
        }
        float mean = s / 65536.f;
        float var = q / 65536.f - mean * mean;
        lstats[c] = mean;
        lstats[128 + c] = rsqrtf(var + 1e-5f);
    }
    __syncthreads();
    int i = blockIdx.x * 256 + threadIdx.x;  // uint4 index (4 dwords = 8 ch)
    uint4 v = ((const uint4*)xin)[i];
    int c0 = ((i * 4) & 63) * 2;  // 64 dwords per pixel (128 ch)
    unsigned ov[4];
    unsigned in[4] = {v.x, v.y, v.z, v.w};
#pragma unroll
    for (int d = 0; d < 4; ++d) {
        int c = c0 + 2 * d;
        f32x2 f = unpk_h2(in[d]);
        float a = fmaxf(0.f, (f.x - lstats[c]) * lstats[128 + c]);
        float b2 = fmaxf(0.f, (f.y - lstats[c + 1]) * lstats[128 + c + 1]);
        ov[d] = f2h2(a, b2);
    }
    ((uint4*)xout)[i] = uint4{ov[0], ov[1], ov[2], ov[3]};
}

// ---- offset/mod conv: NHWC-fp16 direct A-fragment MFMA GEMM ----
// also zeroes the bn praw replicas (blocks 0..7) for the following deform.
template <int C>
__global__ __launch_bounds__(256) void offmod_nhwc(
    const ushort* __restrict__ xh, const ushort* __restrict__ wt,
    const float* __restrict__ b_off, const float* __restrict__ b_mod,
    float* __restrict__ dyb, float* __restrict__ dxb, float* __restrict__ mob,
    float* __restrict__ praw) {
    constexpr int K = C * 9;
    if (blockIdx.x < 8) praw[blockIdx.x * 256 + threadIdx.x] = 0.f;
    const int m0 = blockIdx.x * 64;
    const int b = m0 >> 14;
    const int hw0 = m0 & 16383;
    const int h = hw0 >> 7;
    const int w0 = hw0 & 127;
    const int tid = threadIdx.x;
    const int lane = tid & 63, wv = tid >> 6;
    const int n16 = lane & 15, quad = lane >> 4;
    const int p = wv * 16 + n16;
    const int w = w0 + p;

    int tbase[9];
    bool tval[9];
#pragma unroll
    for (int k = 0; k < 9; ++k) {
        int yy = h + k / 3 - 1, xx = w + k % 3 - 1;
        tval[k] = ((unsigned)yy < 128u) && ((unsigned)xx < 128u);
        int cy = min(max(yy, 0), 127), cx = min(max(xx, 0), 127);
        tbase[k] = ((b << 14) + (cy << 7) + cx) * C + quad * 8;
    }

    f32x4 acc[2];
    acc[0] = (f32x4){0.f, 0.f, 0.f, 0.f};
    acc[1] = (f32x4){0.f, 0.f, 0.f, 0.f};

    const ushort* b0p = wt + (size_t)n16 * K + quad * 8;
    const ushort* b1p = wt + (size_t)(16 + n16) * K + quad * 8;

#pragma unroll
    for (int s = 0; s < K / 32; ++s) {
        const int k = (s * 32) / C;
        const int c0 = (s * 32) % C;
        h8 a = {0, 0, 0, 0, 0, 0, 0, 0};
        if (tval[k]) a = *(const h8*)(xh + (size_t)tbase[k] + c0);
        const h8 bv0 = *(const h8*)(b0p + s * 32);
        const h8 bv1 = *(const h8*)(b1p + s * 32);
        acc[0] = __builtin_amdgcn_mfma_f32_16x16x32_f16(a, bv0, acc[0], 0, 0, 0);
        acc[1] = __builtin_amdgcn_mfma_f32_16x16x32_f16(a, bv1, acc[1], 0, 0, 0);
    }

    __shared__ float sm[32 * 65];
#pragma unroll
    for (int nt = 0; nt < 2; ++nt) {
        int n = nt * 16 + n16;
        int pb = wv * 16 + quad * 4;
#pragma unroll
        for (int r = 0; r < 4; ++r) sm[n * 65 + pb + r] = acc[nt][r];
    }
    __syncthreads();
    {
        int n = tid >> 3, i8 = tid & 7;
        if (n < 27) {
            const float* sp = sm + n * 65 + i8 * 8;
            int px = hw0 + i8 * 8;
            if (n < 18) {
                int k = n >> 1;
                float bias = b_off[n];
                float* dst =
                    ((n & 1) ? dxb : dyb) + (((size_t)(b * 9 + k)) << 14) + px;
#pragma unroll
                for (int j = 0; j < 8; j += 4) {
                    float4 v = make_float4(sp[j] + bias, sp[j + 1] + bias,
                                           sp[j + 2] + bias, sp[j + 3] + bias);
                    *(float4*)(dst + j) = v;
                }
            } else {
                float bias = b_mod[n - 18];
                float* dst = mob + (((size_t)(b * 9 + (n - 18))) << 14) + px;
#pragma unroll
                for (int j = 0; j < 8; j += 4) {
                    float4 v;
                    v.x = 2.f / (1.f + expf(-(sp[j] + bias)));
                    v.y = 2.f / (1.f + expf(-(sp[j + 1] + bias)));
                    v.z = 2.f / (1.f + expf(-(sp[j + 2] + bias)));
                    v.w = 2.f / (1.f + expf(-(sp[j + 3] + bias)));
                    *(float4*)(dst + j) = v;
                }
            }
        }
    }
}

// ---- deformable conv v3 (stage 1): PIX=64, XOR-swizzled LDS A-buffer,
// packed gather table, HALF-batch prefetch (spill-free: q[2][4] = 32 VGPR),
// XCD-contiguous bid swizzle, setprio on MFMA halves. ----
template <int C>
__global__ __launch_bounds__(256, 4) void deform_mfma3(
    const ushort* __restrict__ xh, const float* __restrict__ dyb,
    const float* __restrict__ dxb, const float* __restrict__ mob,
    const ushort* __restrict__ wt, unsigned* __restrict__ xout,
    float* __restrict__ praw) {
    constexpr int PIX = 64;
    constexpr int NCH = C / 8;   // 16B chunks per row
    constexpr int NCC = C / 8;
    constexpr int NIT = PIX * NCC / 256;
    constexpr int HNIT = NIT / 2;
    constexpr int SH = (C / 32) / 2 > 0 ? (C / 32) / 2 : 1;
    constexpr int CPW = C + 8;
    constexpr int KP = ((9 * CPW + 31) / 32) * 32;
    constexpr int ABUF = PIX * C;  // ushorts, no pad (XOR swizzle instead)
    constexpr int LOOPB = 2 * ABUF * 2 + PIX * 9 * 4 + PIX * 9 * 8;
    constexpr int EPIB = 128 * (PIX + 1) * 4;
    constexpr int SMEMB = LOOPB > EPIB ? LOOPB : EPIB;

    __shared__ __align__(16) char smem_raw[SMEMB];
    ushort* abuf0 = (ushort*)smem_raw;
    ushort* abuf1 = abuf0 + ABUF;
    int* tbl = (int*)(abuf0 + 2 * ABUF);
    unsigned* twl = (unsigned*)(smem_raw + 2 * ABUF * 2 + PIX * 9 * 4);

    // XCD-contiguous swizzle: each XCD owns a contiguous 1/8 of the image
    // (grid is a multiple of 8) -> gather working set fits per-XCD L2.
    const int bid = (blockIdx.x & 7) * (gridDim.x >> 3) + (blockIdx.x >> 3);
    const int m0 = bid * PIX;
    const int b = m0 >> 14;
    const int hw0 = m0 & 16383;
    const int h = hw0 >> 7, w0 = hw0 & 127;
    const int tid = threadIdx.x;
    const int lane = tid & 63, wv = tid >> 6;
    const int n16 = lane & 15, quad = lane >> 4;
    const int xr = n16 & (NCH - 1);

    for (int r = tid; r < PIX * 9; r += 256) {
        int p = r & (PIX - 1), k = r >> 6;
        int oi = ((b * 9 + k) << 14) + hw0 + p;
        float py = (float)(h + k / 3 - 1) + dyb[oi];
        float px = (float)(w0 + p + k % 3 - 1) + dxb[oi];
        float mv = mob[oi];
        float y0f = floorf(py), x0f = floorf(px);
        float wy = py - y0f, wx = px - x0f;
        int y0 = (int)y0f, x0 = (int)x0f;
        int y1 = y0 + 1, x1 = x0 + 1;
        float f00 = (1.f - wy) * (1.f - wx) *
                    (((unsigned)y0 < 128u && (unsigned)x0 < 128u) ? mv : 0.f);
        float f01 = (1.f - wy) * wx *
                    (((unsigned)y0 < 128u && (unsigned)x1 < 128u) ? mv : 0.f);
        float f10 = wy * (1.f - wx) *
                    (((unsigned)y1 < 128u && (unsigned)x0 < 128u) ? mv : 0.f);
        float f11 = wy * wx *
                    (((unsigned)y1 < 128u && (unsigned)x1 < 128u) ? mv : 0.f);
        int cy0 = min(max(y0, 0), 127), cy1 = min(max(y1, 0), 127);
        int cx0 = min(max(x0, 0), 127), cx1 = min(max(x1, 0), 127);
        int base00 = (((b << 14) + (cy0 << 7) + cx0)) * C;
        int flags = ((cy1 != cy0) ? 2 : 0) | ((cx1 != cx0) ? 1 : 0);
        int s = p * 9 + k;
        tbl[s] = base00 | flags;
        twl[2 * s] = f2h2(f00, f01);
        twl[2 * s + 1] = f2h2(f10, f11);
    }
    __syncthreads();

    auto issue_loads = [&](int kc, int it0, uint4 (&q)[HNIT][4],
                           uint2 (&fw)[HNIT]) {
#pragma unroll
        for (int j = 0; j < HNIT; ++j) {
            int e = (it0 + j) * 256 + tid;
            int p = e / NCC, cc = e % NCC;
            int s = p * 9 + kc;
            int ent = tbl[s];
            fw[j] = *(const uint2*)&twl[2 * s];
            int base = ent & ~3;
            int dxo = (ent & 1) ? C : 0;
            int dyo = (ent & 2) ? (C << 7) : 0;
            const ushort* pp = xh + (size_t)base + cc * 8;
            q[j][0] = *(const uint4*)(pp);
            q[j][1] = *(const uint4*)(pp + dxo);
            q[j][2] = *(const uint4*)(pp + dyo);
            q[j][3] = *(const uint4*)(pp + dyo + dxo);
        }
    };
    auto interp_write = [&](ushort* dst, int it0, uint4 (&q)[HNIT][4],
                            uint2 (&fw)[HNIT]) {
#pragma unroll
        for (int j = 0; j < HNIT; ++j) {
            int e = (it0 + j) * 256 + tid;
            int p = e / NCC, cc = e % NCC;
            h2 w01, w23;
            __builtin_memcpy(&w01, &fw[j].x, 4);
            __builtin_memcpy(&w23, &fw[j].y, 4);
            h8 F0 = {w01.x, w01.x, w01.x, w01.x, w01.x, w01.x, w01.x, w01.x};
            h8 F1 = {w01.y, w01.y, w01.y, w01.y, w01.y, w01.y, w01.y, w01.y};
            h8 F2 = {w23.x, w23.x, w23.x, w23.x, w23.x, w23.x, w23.x, w23.x};
            h8 F3 = {w23.y, w23.y, w23.y, w23.y, w23.y, w23.y, w23.y, w23.y};
            h8 a0, a1, a2, a3;
            __builtin_memcpy(&a0, &q[j][0], 16);
            __builtin_memcpy(&a1, &q[j][1], 16);
            __builtin_memcpy(&a2, &q[j][2], 16);
            __builtin_memcpy(&a3, &q[j][3], 16);
            h8 v = a0 * F0 + a1 * F1 + a2 * F2 + a3 * F3;
            uint4 ov;
            __builtin_memcpy(&ov, &v, 16);
            int ccs = cc ^ (p & (NCH - 1));
            *(uint4*)&dst[p * C + ccs * 8] = ov;
        }
    };

    f32x4 acc[4][2];
#pragma unroll
    for (int mt = 0; mt < 4; ++mt)
#pragma unroll
        for (int nt = 0; nt < 2; ++nt) acc[mt][nt] = (f32x4){0.f, 0.f, 0.f, 0.f};

    const ushort* bbase[2];
#pragma unroll
    for (int nt = 0; nt < 2; ++nt)
        bbase[nt] = wt + (size_t)(wv * 32 + nt * 16 + n16) * KP + quad * 8;

    auto mfma_run = [&](const ushort* ab, int kc, int s0, int s1) {
#pragma unroll
        for (int s = s0; s < s1; ++s) {
            h8 av[4], bv[2];
            int ch = (s * 4 + quad) ^ xr;
#pragma unroll
            for (int mt = 0; mt < 4; ++mt)
                av[mt] = *(const h8*)(ab + (mt * 16 + n16) * C + ch * 8);
#pragma unroll
            for (int nt = 0; nt < 2; ++nt)
                bv[nt] = *(const h8*)(bbase[nt] + kc * CPW + s * 32);
#pragma unroll
            for (int mt = 0; mt < 4; ++mt)
#pragma unroll
                for (int nt = 0; nt < 2; ++nt)
                    acc[mt][nt] = __builtin_amdgcn_mfma_f32_16x16x32_f16(
                        av[mt], bv[nt], acc[mt][nt], 0, 0, 0);
        }
    };

    {
        uint4 q[HNIT][4];
        uint2 fw[HNIT];
        issue_loads(0, 0, q, fw);
        interp_write(abuf0, 0, q, fw);
        issue_loads(0, HNIT, q, fw);
        interp_write(abuf0, HNIT, q, fw);
    }
    __syncthreads();

#pragma unroll 1
    for (int kc = 0; kc < 9; ++kc) {
        const ushort* ab = (kc & 1) ? abuf1 : abuf0;
        ushort* dst = (kc & 1) ? abuf0 : abuf1;
        uint4 q[HNIT][4];
        uint2 fw[HNIT];
        if (kc < 8) issue_loads(kc + 1, 0, q, fw);
        __builtin_amdgcn_s_setprio(1);
        mfma_run(ab, kc, 0, SH);
        __builtin_amdgcn_s_setprio(0);
        if (kc < 8) {
            interp_write(dst, 0, q, fw);
            issue_loads(kc + 1, HNIT, q, fw);
        }
        __builtin_amdgcn_s_setprio(1);
        mfma_run(ab, kc, SH, C / 32);
        __builtin_amdgcn_s_setprio(0);
        if (kc < 8) interp_write(dst, HNIT, q, fw);
        __syncthreads();
    }

    // ---- epilogue: transpose via LDS; bn stats (fp32) + raw fp16 NHWC out ----
    float* sm = (float*)smem_raw;
    constexpr int SROW = PIX + 1;
#pragma unroll
    for (int mt = 0; mt < 4; ++mt)
#pragma unroll
        for (int nt = 0; nt < 2; ++nt) {
            int o = wv * 32 + nt * 16 + n16;
            int mb = mt * 16 + quad * 4;
#pragma unroll
            for (int r = 0; r < 4; ++r) sm[o * SROW + mb + r] = acc[mt][nt][r];
        }
    __syncthreads();
    {
        // stats: thread = (o, half), 32 px each, fp32-accurate
        int o = tid >> 1, half = tid & 1;
        const float* sp = sm + o * SROW + half * 32;
        float s = 0.f, qq = 0.f;
#pragma unroll
        for (int i = 0; i < 32; i += 4) {
            float4 v = make_float4(sp[i], sp[i + 1], sp[i + 2], sp[i + 3]);
            s += v.x + v.y + v.z + v.w;
            qq += v.x * v.x + v.y * v.y + v.z * v.z + v.w * v.w;
        }
        s += __shfl_down(s, 1, 64);
        qq += __shfl_down(qq, 1, 64);
        if (half == 0) {
            float* pr = praw + (blockIdx.x & 7) * 256;
            atomicAdd(&pr[o], s);
            atomicAdd(&pr[128 + o], qq);
        }
    }
    {
        // NHWC fp16 raw write: thread = (p = tid>>2, cc4 = tid&3), 32 ch
        int p = tid >> 2, cc4 = tid & 3;
        unsigned ov[16];
#pragma unroll
        for (int j = 0; j < 16; ++j) {
            int c = cc4 * 32 + 2 * j;
            ov[j] = f2h2(sm[c * SROW + p], sm[(c + 1) * SROW + p]);
        }
        uint4* dst = (uint4*)(xout + ((size_t)(m0 + p)) * 64 + cc4 * 16);
        dst[0] = uint4{ov[0], ov[1], ov[2], ov[3]};
        dst[1] = uint4{ov[4], ov[5], ov[6], ov[7]};
        dst[2] = uint4{ov[8], ov[9], ov[10], ov[11]};
        dst[3] = uint4{ov[12], ov[13], ov[14], ov[15]};
    }
}

// ---- deformable conv stage-2: PIX=64 (2 rows x 32 cols) -> REGISTER-ONLY
// epilogue: bn stats via shfl_xor, 2x2 pool lane-local (R7-validated mapping,
// adapted to PIX=64). Removes the LDS-transpose epilogue's 4-way conflicts. ----
template <int C>
__global__ __launch_bounds__(256, 4) void deform_mfma3p(
    const ushort* __restrict__ xh, const float* __restrict__ dyb,
    const float* __restrict__ dxb, const float* __restrict__ mob,
    const ushort* __restrict__ wt, float* __restrict__ pout,
    float* __restrict__ praw) {
    constexpr int PIX = 64;
    constexpr int NCH = C / 8;
    constexpr int NCC = C / 8;
    constexpr int NIT = PIX * NCC / 256;
    constexpr int HNIT = NIT / 2;
    constexpr int SH = (C / 32) / 2 > 0 ? (C / 32) / 2 : 1;
    constexpr int CPW = C + 8;
    constexpr int KP = ((9 * CPW + 31) / 32) * 32;
    constexpr int ABUF = PIX * C;
    constexpr int SMEMB = 2 * ABUF * 2 + PIX * 9 * 4 + PIX * 9 * 8;

    __shared__ __align__(16) char smem_raw[SMEMB];
    ushort* abuf0 = (ushort*)smem_raw;
    ushort* abuf1 = abuf0 + ABUF;
    int* tbl = (int*)(abuf0 + 2 * ABUF);
    unsigned* twl = (unsigned*)(smem_raw + 2 * ABUF * 2 + PIX * 9 * 4);

    // XCD-contiguous swizzle, then bid = b*256 + rp*4 + g
    const int bid = (blockIdx.x & 7) * (gridDim.x >> 3) + (blockIdx.x >> 3);
    const int b = bid >> 8;
    const int rp = (bid >> 2) & 63;
    const int g = bid & 3;
    const int tid = threadIdx.x;
    const int lane = tid & 63, wv = tid >> 6;
    const int n16 = lane & 15, quad = lane >> 4;
    const int xr = n16 & (NCH - 1);

    // pixel p in [0,64): row = 2*rp + (p>>5), col = g*32 + (p&31)
    for (int r = tid; r < PIX * 9; r += 256) {
        int p = r & (PIX - 1), k = r >> 6;
        int row = 2 * rp + (p >> 5), col = g * 32 + (p & 31);
        int oi = ((b * 9 + k) << 14) + (row << 7) + col;
        float py = (float)(row + k / 3 - 1) + dyb[oi];
        float px = (float)(col + k % 3 - 1) + dxb[oi];
        float mv = mob[oi];
        float y0f = floorf(py), x0f = floorf(px);
        float wy = py - y0f, wx = px - x0f;
        int y0 = (int)y0f, x0 = (int)x0f;
        int y1 = y0 + 1, x1 = x0 + 1;
        float f00 = (1.f - wy) * (1.f - wx) *
                    (((unsigned)y0 < 128u && (unsigned)x0 < 128u) ? mv : 0.f);
        float f01 = (1.f - wy) * wx *
                    (((unsigned)y0 < 128u && (unsigned)x1 < 128u) ? mv : 0.f);
        float f10 = wy * (1.f - wx) *
                    (((unsigned)y1 < 128u && (unsigned)x0 < 128u) ? mv : 0.f);
        float f11 = wy * wx *
                    (((unsigned)y1 < 128u && (unsigned)x1 < 128u) ? mv : 0.f);
        int cy0 = min(max(y0, 0), 127), cy1 = min(max(y1, 0), 127);
        int cx0 = min(max(x0, 0), 127), cx1 = min(max(x1, 0), 127);
        int base00 = (((b << 14) + (cy0 << 7) + cx0)) * C;
        int flags = ((cy1 != cy0) ? 2 : 0) | ((cx1 != cx0) ? 1 : 0);
        int s = p * 9 + k;
        tbl[s] = base00 | flags;
        twl[2 * s] = f2h2(f00, f01);
        twl[2 * s + 1] = f2h2(f10, f11);
    }
    __syncthreads();

    auto issue_loads = [&](int kc, int it0, uint4 (&q)[HNIT][4],
                           uint2 (&fw)[HNIT]) {
#pragma unroll
        for (int j = 0; j < HNIT; ++j) {
            int e = (it0 + j) * 256 + tid;
            int p = e / NCC, cc = e % NCC;
            int s = p * 9 + kc;
            int ent = tbl[s];
            fw[j] = *(const uint2*)&twl[2 * s];
            int base = ent & ~3;
            int dxo = (ent & 1) ? C : 0;
            int dyo = (ent & 2) ? (C << 7) : 0;
            const ushort* pp = xh + (size_t)base + cc * 8;
            q[j][0] = *(const uint4*)(pp);
            q[j][1] = *(const uint4*)(pp + dxo);
            q[j][2] = *(const uint4*)(pp + dyo);
            q[j][3] = *(const uint4*)(pp + dyo + dxo);
        }
    };
    auto interp_write = [&](ushort* dst, int it0, uint4 (&q)[HNIT][4],
                            uint2 (&fw)[HNIT]) {
#pragma unroll
        for (int j = 0; j < HNIT; ++j) {
            int e = (it0 + j) * 256 + tid;
            int p = e / NCC, cc = e % NCC;
            h2 w01, w23;
            __builtin_memcpy(&w01, &fw[j].x, 4);
            __builtin_memcpy(&w23, &fw[j].y, 4);
            h8 F0 = {w01.x, w01.x, w01.x, w01.x, w01.x, w01.x, w01.x, w01.x};
            h8 F1 = {w01.y, w01.y, w01.y, w01.y, w01.y, w01.y, w01.y, w01.y};
            h8 F2 = {w23.x, w23.x, w23.x, w23.x, w23.x, w23.x, w23.x, w23.x};
            h8 F3 = {w23.y, w23.y, w23.y, w23.y, w23.y, w23.y, w23.y, w23.y};
            h8 a0, a1, a2, a3;
            __builtin_memcpy(&a0, &q[j][0], 16);
            __builtin_memcpy(&a1, &q[j][1], 16);
            __builtin_memcpy(&a2, &q[j][2], 16);
            __builtin_memcpy(&a3, &q[j][3], 16);
            h8 v = a0 * F0 + a1 * F1 + a2 * F2 + a3 * F3;
            uint4 ov;
            __builtin_memcpy(&ov, &v, 16);
            int ccs = cc ^ (p & (NCH - 1));
            *(uint4*)&dst[p * C + ccs * 8] = ov;
        }
    };

    f32x4 acc[4][2];
#pragma unroll
    for (int mt = 0; mt < 4; ++mt)
#pragma unroll
        for (int nt = 0; nt < 2; ++nt) acc[mt][nt] = (f32x4){0.f, 0.f, 0.f, 0.f};

    const ushort* bbase[2];
#pragma unroll
    for (int nt = 0; nt < 2; ++nt)
        bbase[nt] = wt + (size_t)(wv * 32 + nt * 16 + n16) * KP + quad * 8;

    auto mfma_run = [&](const ushort* ab, int kc, int s0, int s1) {
#pragma unroll
        for (int s = s0; s < s1; ++s) {
            h8 av[4], bv[2];
            int ch = (s * 4 + quad) ^ xr;
#pragma unroll
            for (int mt = 0; mt < 4; ++mt)
                av[mt] = *(const h8*)(ab + (mt * 16 + n16) * C + ch * 8);
#pragma unroll
            for (int nt = 0; nt < 2; ++nt)
                bv[nt] = *(const h8*)(bbase[nt] + kc * CPW + s * 32);
#pragma unroll
            for (int mt = 0; mt < 4; ++mt)
#pragma unroll
                for (int nt = 0; nt < 2; ++nt)
                    acc[mt][nt] = __builtin_amdgcn_mfma_f32_16x16x32_f16(
                        av[mt], bv[nt], acc[mt][nt], 0, 0, 0);
        }
    };

    {
        uint4 q[HNIT][4];
        uint2 fw[HNIT];
        issue_loads(0, 0, q, fw);
        interp_write(abuf0, 0, q, fw);
        issue_loads(0, HNIT, q, fw);
        interp_write(abuf0, HNIT, q, fw);
    }
    __syncthreads();

#pragma unroll 1
    for (int kc = 0; kc < 9; ++kc) {
        const ushort* ab = (kc & 1) ? abuf1 : abuf0;
        ushort* dst = (kc & 1) ? abuf0 : abuf1;
        uint4 q[HNIT][4];
        uint2 fw[HNIT];
        if (kc < 8) issue_loads(kc + 1, 0, q, fw);
        __builtin_amdgcn_s_setprio(1);
        mfma_run(ab, kc, 0, SH);
        __builtin_amdgcn_s_setprio(0);
        if (kc < 8) {
            interp_write(dst, 0, q, fw);
            issue_loads(kc + 1, HNIT, q, fw);
        }
        __builtin_amdgcn_s_setprio(1);
        mfma_run(ab, kc, SH, C / 32);
        __builtin_amdgcn_s_setprio(0);
        if (kc < 8) interp_write(dst, HNIT, q, fw);
        __syncthreads();
    }

    // ---- epilogue: register-only bn stats + register 2x2 pool ----
    // acc[mt][nt][r]: o = wv*32 + nt*16 + n16 ; p = mt*16 + quad*4 + r
    // row-half = p>>5 = mt>>1 ; col = p&31 = (mt&1)*16 + quad*4 + r
#pragma unroll
    for (int nt = 0; nt < 2; ++nt) {
        int o = wv * 32 + nt * 16 + n16;
        float s = 0.f, qq = 0.f;
#pragma unroll
        for (int mt = 0; mt < 4; ++mt)
#pragma unroll
            for (int r = 0; r < 4; ++r) {
                float v = acc[mt][nt][r];
                s += v;
                qq += v * v;
            }
        s += __shfl_xor(s, 16, 64);
        s += __shfl_xor(s, 32, 64);
        qq += __shfl_xor(qq, 16, 64);
        qq += __shfl_xor(qq, 32, 64);
        if (quad == 0) {
            float* pr = praw + (blockIdx.x & 7) * 256;
            atomicAdd(&pr[o], s);
            atomicAdd(&pr[128 + o], qq);
        }
        // pool: rows = (mt, mt+2) for mt in {0,1}; col pairs = r pairs.
        // pooled local col pc = mt*8 + quad*2 + rp2  (in [0,16))
        float* po = pout + (((size_t)(b * 128 + o)) << 12) + rp * 64 + g * 16;
#pragma unroll
        for (int mt = 0; mt < 2; ++mt)
#pragma unroll
            for (int rp2 = 0; rp2 < 2; ++rp2) {
                float m = fmaxf(
                    fmaxf(acc[mt][nt][2 * rp2], acc[mt][nt][2 * rp2 + 1]),
                    fmaxf(acc[mt + 2][nt][2 * rp2],
                          acc[mt + 2][nt][2 * rp2 + 1]));
                po[mt * 8 + quad * 2 + rp2] = m;
            }
    }
}

// ---- pooled normalize: out = relu((pout - mean) * rstd) ----
__global__ __launch_bounds__(256) void pool_norm(const float* __restrict__ pout,
                                                 const float* __restrict__ praw,
                                                 float* __restrict__ out) {
    __shared__ float lstats[256];
    if (threadIdx.x < 128) {
        int c = threadIdx.x;
        float s = 0.f, q = 0.f;
#pragma unroll
        for (int r = 0; r < 8; ++r) {
            s += praw[r * 256 + c];
            q += praw[r * 256 + 128 + c];
        }
        float mean = s / 65536.f;
        float var = q / 65536.f - mean * mean;
        lstats[c] = mean;
        lstats[128 + c] = rsqrtf(var + 1e-5f);
    }
    __syncthreads();
    int i = blockIdx.x * 256 + threadIdx.x;  // float4 index, total 524288
    int c = (i >> 10) & 127;
    float mean = lstats[c], rstd = lstats[128 + c];
    float4 v = ((const float4*)pout)[i];
    v.x = fmaxf(0.f, (v.x - mean) * rstd);
    v.y = fmaxf(0.f, (v.y - mean) * rstd);
    v.z = fmaxf(0.f, (v.z - mean) * rstd);
    v.w = fmaxf(0.f, (v.w - mean) * rstd);
    ((float4*)out)[i] = v;
}

extern "C" void kernel_launch(void* const* d_in, const int* in_sizes, int n_in,
                              void* d_out, int out_size, void* d_ws,
                              size_t ws_size, hipStream_t stream) {
    (void)in_sizes;
    (void)n_in;
    (void)out_size;
    (void)ws_size;
    const float* x = (const float*)d_in[0];
    const float* w_off1 = (const float*)d_in[1];
    const float* b_off1 = (const float*)d_in[2];
    const float* w_mod1 = (const float*)d_in[3];
    const float* b_mod1 = (const float*)d_in[4];
    const float* w1 = (const float*)d_in[5];
    const float* w_off2 = (const float*)d_in[6];
    const float* b_off2 = (const float*)d_in[7];
    const float* w_mod2 = (const float*)d_in[8];
    const float* b_mod2 = (const float*)d_in[9];
    const float* w2 = (const float*)d_in[10];
    float* out = (float*)d_out;
    float* ws = (float*)d_ws;

    // KP1 = 672 (C=64, CP=72), KP2 = 1248 (C=128, CP=136)
    ushort* Wt1 = (ushort*)ws;                            // 86016 ush = 43008 f
    ushort* Wt2 = (ushort*)(ws + 43008);                  // 159744 ush = 79872 f
    ushort* Wo1 = (ushort*)(ws + 43008 + 79872);          // need 18432 ush
    ushort* Wo2 = (ushort*)(ws + 43008 + 79872 + 16384);  // need 36864 ush
    float* dyb = ws + 172032;
    float* dxb = dyb + 589824;
    float* mob = dxb + 589824;
    float* hbuf = mob + 589824;      // h1 raw fp16 NHWC (4M f); later pout (2M f)
    float* xhf = hbuf + 8388608;     // 2097152 f: x as NHWC fp16
    float* h1hf = xhf + 2097152;     // 4194304 f: h1 normalized NHWC fp16
    float* praw = h1hf + 4194304;    // 2048 (8 replicas x 256)
    ushort* xh = (ushort*)xhf;
    ushort* h1h = (ushort*)h1hf;

    prep_weights<<<1176, 256, 0, stream>>>(w1, w2, w_off1, w_mod1, w_off2,
                                           w_mod2, Wt1, Wt2, Wo1, Wo2);

    // ---- stage 1 ----
    nhwc_cvt<64><<<1024, 256, 0, stream>>>(x, (unsigned*)xh);
    offmod_nhwc<64><<<1024, 256, 0, stream>>>(xh, Wo1, b_off1, b_mod1, dyb, dxb,
                                              mob, praw);
    deform_mfma3<64><<<1024, 256, 0, stream>>>(xh, dyb, dxb, mob, Wt1,
                                               (unsigned*)hbuf, praw);
    bn_apply_ew<<<4096, 256, 0, stream>>>((const unsigned*)hbuf, praw,
                                          (unsigned*)h1h);

    // ---- stage 2 ----
    offmod_nhwc<128><<<1024, 256, 0, stream>>>(h1h, Wo2, b_off2, b_mod2, dyb,
                                               dxb, mob, praw);
    // hbuf (h1 raw) is dead after bn_apply_ew: reuse for pooled raw max
    deform_mfma3p<128><<<1024, 256, 0, stream>>>(h1h, dyb, dxb, mob, Wt2, hbuf,
                                                 praw);
    pool_norm<<<2048, 256, 0, stream>>>(hbuf, praw, out);
}

// Round 9
// 250.571 us; speedup vs baseline: 1.1950x; 1.0090x over previous
//
#include <hip/hip_runtime.h>
#include <math.h>

#define HH 128
#define WW 128
#define HWSZ 16384

typedef __attribute__((ext_vector_type(8))) _Float16 h8;
typedef __attribute__((ext_vector_type(2))) _Float16 h2;
typedef __attribute__((ext_vector_type(4))) float f32x4;
typedef __attribute__((ext_vector_type(2))) float f32x2;
typedef unsigned short ushort;

// fp16 conversion helpers (RNE via scalar cast)
__device__ __forceinline__ ushort f2h(float f) {
    _Float16 h = (_Float16)f;
    ushort u;
    __builtin_memcpy(&u, &h, 2);
    return u;
}
// pack two floats -> packed fp16 dword (lo in [15:0], hi in [31:16])
__device__ __forceinline__ unsigned f2h2(float lo, float hi) {
    h2 r;
    r.x = (_Float16)lo;
    r.y = (_Float16)hi;
    unsigned u;
    __builtin_memcpy(&u, &r, 4);
    return u;
}
// unpack 2 packed fp16 (one dword) to float2
__device__ __forceinline__ f32x2 unpk_h2(unsigned u) {
    h2 h;
    __builtin_memcpy(&h, &u, 4);
    return (f32x2){(float)h.x, (float)h.y};
}
// fused per-channel normalize + relu on 8 packed fp16: max(a*R + N, 0)
__device__ __forceinline__ h8 nrelu8(h8 a, h8 R, h8 N) {
    h8 t = a * R + N;
#if __has_builtin(__builtin_elementwise_max)
    h8 z = {};
    return __builtin_elementwise_max(t, z);
#else
    h8 r;
#pragma unroll
    for (int i = 0; i < 8; ++i)
        r[i] = t[i] > (_Float16)0 ? t[i] : (_Float16)0;
    return r;
#endif
}

// ---- merged weight prep: wpad1 | wpad2 | woff1 | woff2 in one launch ----
__global__ __launch_bounds__(256) void prep_weights(
    const float* __restrict__ w1, const float* __restrict__ w2,
    const float* __restrict__ w_off1, const float* __restrict__ w_mod1,
    const float* __restrict__ w_off2, const float* __restrict__ w_mod2,
    ushort* __restrict__ Wt1, ushort* __restrict__ Wt2,
    ushort* __restrict__ Wo1, ushort* __restrict__ Wo2) {
    int bid = blockIdx.x, tid = threadIdx.x;
    if (bid < 336) {
        int i = bid * 256 + tid;
        int o = i / 672, kq = i % 672;
        int k = kq / 72, c = kq % 72;
        float v = (k < 9 && c < 64) ? w1[(o * 64 + c) * 9 + k] : 0.f;
        Wt1[i] = f2h(v);
    } else if (bid < 960) {
        int i = (bid - 336) * 256 + tid;
        int o = i / 1248, kq = i % 1248;
        int k = kq / 136, c = kq % 136;
        float v = (k < 9 && c < 128) ? w2[(o * 128 + c) * 9 + k] : 0.f;
        Wt2[i] = f2h(v);
    } else if (bid < 1032) {
        int i = (bid - 960) * 256 + tid;  // < 32*576
        int o = i / 576, kap = i % 576;
        int k = kap / 64, c = kap % 64;
        float v = 0.f;
        if (o < 18) v = w_off1[(o * 64 + c) * 9 + k];
        else if (o < 27) v = w_mod1[((o - 18) * 64 + c) * 9 + k];
        Wo1[i] = f2h(v);
    } else {
        int i = (bid - 1032) * 256 + tid;  // < 32*1152
        int o = i / 1152, kap = i % 1152;
        int k = kap / 128, c = kap % 128;
        float v = 0.f;
        if (o < 18) v = w_off2[(o * 128 + c) * 9 + k];
        else if (o < 27) v = w_mod2[((o - 18) * 128 + c) * 9 + k];
        Wo2[i] = f2h(v);
    }
}

// ---- NCHW fp32 -> NHWC fp16 converter (tiled transpose) ----
template <int C>
__global__ __launch_bounds__(256) void nhwc_cvt(const float* __restrict__ xin,
                                                unsigned* __restrict__ xout) {
    __shared__ float tile[64][C + 1];
    const int m0 = blockIdx.x * 64;
    const int b = m0 >> 14;
    const int hw0 = m0 & 16383;
    const int t = threadIdx.x;
    const int pr = t & 63, cr = t >> 6;
#pragma unroll
    for (int it = 0; it < C / 4; ++it) {
        int c = it * 4 + cr;
        tile[pr][c] = xin[(((size_t)(b * C + c)) << 14) + hw0 + pr];
    }
    __syncthreads();
    constexpr int CH = C / 2;
#pragma unroll
    for (int it = 0; it < 64 * CH / 256; ++it) {
        int slot = it * 256 + t;
        int p = slot / CH, cc = slot % CH;
        xout[(size_t)(m0 + p) * CH + cc] =
            f2h2(tile[p][2 * cc], tile[p][2 * cc + 1]);
    }
}

// ---- offset/mod conv: NHWC-fp16 direct A-fragment MFMA GEMM ----
// NORM: read RAW input + inline bn (stats from pr_in replicas).
// also zeroes the praw_out replicas for the following deform.
template <int C, bool NORM>
__global__ __launch_bounds__(256) void offmod_nhwc(
    const ushort* __restrict__ xh, const ushort* __restrict__ wt,
    const float* __restrict__ b_off, const float* __restrict__ b_mod,
    float* __restrict__ dyb, float* __restrict__ dxb, float* __restrict__ mob,
    float* __restrict__ praw_out, const float* __restrict__ pr_in) {
    constexpr int K = C * 9;
    __shared__ unsigned cstat[128];  // rstd2[64] | nmr2[64]
    if (blockIdx.x < 8) praw_out[blockIdx.x * 256 + threadIdx.x] = 0.f;
    const int m0 = blockIdx.x * 64;
    const int b = m0 >> 14;
    const int hw0 = m0 & 16383;
    const int h = hw0 >> 7;
    const int w0 = hw0 & 127;
    const int tid = threadIdx.x;
    const int lane = tid & 63, wv = tid >> 6;
    const int n16 = lane & 15, quad = lane >> 4;
    const int p = wv * 16 + n16;
    const int w = w0 + p;

    if (NORM) {
        if (tid < 64) {
            int c0i = 2 * tid, c1i = 2 * tid + 1;
            float s0 = 0.f, q0 = 0.f, s1 = 0.f, q1 = 0.f;
#pragma unroll
            for (int r = 0; r < 8; ++r) {
                s0 += pr_in[r * 256 + c0i];
                q0 += pr_in[r * 256 + 128 + c0i];
                s1 += pr_in[r * 256 + c1i];
                q1 += pr_in[r * 256 + 128 + c1i];
            }
            float m0v = s0 / 65536.f, m1v = s1 / 65536.f;
            float r0 = rsqrtf(q0 / 65536.f - m0v * m0v + 1e-5f);
            float r1 = rsqrtf(q1 / 65536.f - m1v * m1v + 1e-5f);
            cstat[tid] = f2h2(r0, r1);
            cstat[64 + tid] = f2h2(-m0v * r0, -m1v * r1);
        }
        __syncthreads();
    }

    h8 Rv[4], Nv[4];
    if (NORM) {
#pragma unroll
        for (int si = 0; si < 4; ++si) {
            int db = si * 16 + quad * 4;
            Rv[si] = *(const h8*)&cstat[db];
            Nv[si] = *(const h8*)&cstat[64 + db];
        }
    }

    int tbase[9];
    bool tval[9];
#pragma unroll
    for (int k = 0; k < 9; ++k) {
        int yy = h + k / 3 - 1, xx = w + k % 3 - 1;
        tval[k] = ((unsigned)yy < 128u) && ((unsigned)xx < 128u);
        int cy = min(max(yy, 0), 127), cx = min(max(xx, 0), 127);
        tbase[k] = ((b << 14) + (cy << 7) + cx) * C + quad * 8;
    }

    f32x4 acc[2];
    acc[0] = (f32x4){0.f, 0.f, 0.f, 0.f};
    acc[1] = (f32x4){0.f, 0.f, 0.f, 0.f};

    const ushort* b0p = wt + (size_t)n16 * K + quad * 8;
    const ushort* b1p = wt + (size_t)(16 + n16) * K + quad * 8;

#pragma unroll
    for (int s = 0; s < K / 32; ++s) {
        const int k = (s * 32) / C;
        const int c0 = (s * 32) % C;
        h8 a = {0, 0, 0, 0, 0, 0, 0, 0};
        if (tval[k]) {
            a = *(const h8*)(xh + (size_t)tbase[k] + c0);
            if (NORM) {
                const int si = s & ((C / 32) - 1);
                a = nrelu8(a, Rv[si], Nv[si]);
            }
        }
        const h8 bv0 = *(const h8*)(b0p + s * 32);
        const h8 bv1 = *(const h8*)(b1p + s * 32);
        acc[0] = __builtin_amdgcn_mfma_f32_16x16x32_f16(a, bv0, acc[0], 0, 0, 0);
        acc[1] = __builtin_amdgcn_mfma_f32_16x16x32_f16(a, bv1, acc[1], 0, 0, 0);
    }

    __shared__ float sm[32 * 65];
#pragma unroll
    for (int nt = 0; nt < 2; ++nt) {
        int n = nt * 16 + n16;
        int pb = wv * 16 + quad * 4;
#pragma unroll
        for (int r = 0; r < 4; ++r) sm[n * 65 + pb + r] = acc[nt][r];
    }
    __syncthreads();
    {
        int n = tid >> 3, i8 = tid & 7;
        if (n < 27) {
            const float* sp = sm + n * 65 + i8 * 8;
            int px = hw0 + i8 * 8;
            if (n < 18) {
                int k = n >> 1;
                float bias = b_off[n];
                float* dst =
                    ((n & 1) ? dxb : dyb) + (((size_t)(b * 9 + k)) << 14) + px;
#pragma unroll
                for (int j = 0; j < 8; j += 4) {
                    float4 v = make_float4(sp[j] + bias, sp[j + 1] + bias,
                                           sp[j + 2] + bias, sp[j + 3] + bias);
                    *(float4*)(dst + j) = v;
                }
            } else {
                float bias = b_mod[n - 18];
                float* dst = mob + (((size_t)(b * 9 + (n - 18))) << 14) + px;
#pragma unroll
                for (int j = 0; j < 8; j += 4) {
                    float4 v;
                    v.x = 2.f / (1.f + expf(-(sp[j] + bias)));
                    v.y = 2.f / (1.f + expf(-(sp[j + 1] + bias)));
                    v.z = 2.f / (1.f + expf(-(sp[j + 2] + bias)));
                    v.w = 2.f / (1.f + expf(-(sp[j + 3] + bias)));
                    *(float4*)(dst + j) = v;
                }
            }
        }
    }
}

// ---- deformable conv v3 (stage 1): PIX=64, XOR-swizzled LDS A-buffer,
// packed gather table, HALF-batch prefetch (spill-free: q[2][4] = 32 VGPR),
// XCD-contiguous bid swizzle, setprio on MFMA halves. (R5-proven form) ----
template <int C>
__global__ __launch_bounds__(256, 4) void deform_mfma3(
    const ushort* __restrict__ xh, const float* __restrict__ dyb,
    const float* __restrict__ dxb, const float* __restrict__ mob,
    const ushort* __restrict__ wt, unsigned* __restrict__ xout,
    float* __restrict__ praw) {
    constexpr int PIX = 64;
    constexpr int NCH = C / 8;   // 16B chunks per row
    constexpr int NCC = C / 8;
    constexpr int NIT = PIX * NCC / 256;
    constexpr int HNIT = NIT / 2;
    constexpr int SH = (C / 32) / 2 > 0 ? (C / 32) / 2 : 1;
    constexpr int CPW = C + 8;
    constexpr int KP = ((9 * CPW + 31) / 32) * 32;
    constexpr int ABUF = PIX * C;  // ushorts, no pad (XOR swizzle instead)
    constexpr int LOOPB = 2 * ABUF * 2 + PIX * 9 * 4 + PIX * 9 * 8;
    constexpr int EPIB = 128 * (PIX + 1) * 4;
    constexpr int SMEMB = LOOPB > EPIB ? LOOPB : EPIB;

    __shared__ __align__(16) char smem_raw[SMEMB];
    ushort* abuf0 = (ushort*)smem_raw;
    ushort* abuf1 = abuf0 + ABUF;
    int* tbl = (int*)(abuf0 + 2 * ABUF);
    unsigned* twl = (unsigned*)(smem_raw + 2 * ABUF * 2 + PIX * 9 * 4);

    // XCD-contiguous swizzle: each XCD owns a contiguous 1/8 of the image
    const int bid = (blockIdx.x & 7) * (gridDim.x >> 3) + (blockIdx.x >> 3);
    const int m0 = bid * PIX;
    const int b = m0 >> 14;
    const int hw0 = m0 & 16383;
    const int h = hw0 >> 7, w0 = hw0 & 127;
    const int tid = threadIdx.x;
    const int lane = tid & 63, wv = tid >> 6;
    const int n16 = lane & 15, quad = lane >> 4;
    const int xr = n16 & (NCH - 1);

    for (int r = tid; r < PIX * 9; r += 256) {
        int p = r & (PIX - 1), k = r >> 6;
        int oi = ((b * 9 + k) << 14) + hw0 + p;
        float py = (float)(h + k / 3 - 1) + dyb[oi];
        float px = (float)(w0 + p + k % 3 - 1) + dxb[oi];
        float mv = mob[oi];
        float y0f = floorf(py), x0f = floorf(px);
        float wy = py - y0f, wx = px - x0f;
        int y0 = (int)y0f, x0 = (int)x0f;
        int y1 = y0 + 1, x1 = x0 + 1;
        float f00 = (1.f - wy) * (1.f - wx) *
                    (((unsigned)y0 < 128u && (unsigned)x0 < 128u) ? mv : 0.f);
        float f01 = (1.f - wy) * wx *
                    (((unsigned)y0 < 128u && (unsigned)x1 < 128u) ? mv : 0.f);
        float f10 = wy * (1.f - wx) *
                    (((unsigned)y1 < 128u && (unsigned)x0 < 128u) ? mv : 0.f);
        float f11 = wy * wx *
                    (((unsigned)y1 < 128u && (unsigned)x1 < 128u) ? mv : 0.f);
        int cy0 = min(max(y0, 0), 127), cy1 = min(max(y1, 0), 127);
        int cx0 = min(max(x0, 0), 127), cx1 = min(max(x1, 0), 127);
        int base00 = (((b << 14) + (cy0 << 7) + cx0)) * C;
        int flags = ((cy1 != cy0) ? 2 : 0) | ((cx1 != cx0) ? 1 : 0);
        int s = p * 9 + k;
        tbl[s] = base00 | flags;
        twl[2 * s] = f2h2(f00, f01);
        twl[2 * s + 1] = f2h2(f10, f11);
    }
    __syncthreads();

    auto issue_loads = [&](int kc, int it0, uint4 (&q)[HNIT][4],
                           uint2 (&fw)[HNIT]) {
#pragma unroll
        for (int j = 0; j < HNIT; ++j) {
            int e = (it0 + j) * 256 + tid;
            int p = e / NCC, cc = e % NCC;
            int s = p * 9 + kc;
            int ent = tbl[s];
            fw[j] = *(const uint2*)&twl[2 * s];
            int base = ent & ~3;
            int dxo = (ent & 1) ? C : 0;
            int dyo = (ent & 2) ? (C << 7) : 0;
            const ushort* pp = xh + (size_t)base + cc * 8;
            q[j][0] = *(const uint4*)(pp);
            q[j][1] = *(const uint4*)(pp + dxo);
            q[j][2] = *(const uint4*)(pp + dyo);
            q[j][3] = *(const uint4*)(pp + dyo + dxo);
        }
    };
    auto interp_write = [&](ushort* dst, int it0, uint4 (&q)[HNIT][4],
                            uint2 (&fw)[HNIT]) {
#pragma unroll
        for (int j = 0; j < HNIT; ++j) {
            int e = (it0 + j) * 256 + tid;
            int p = e / NCC, cc = e % NCC;
            h2 w01, w23;
            __builtin_memcpy(&w01, &fw[j].x, 4);
            __builtin_memcpy(&w23, &fw[j].y, 4);
            h8 F0 = {w01.x, w01.x, w01.x, w01.x, w01.x, w01.x, w01.x, w01.x};
            h8 F1 = {w01.y, w01.y, w01.y, w01.y, w01.y, w01.y, w01.y, w01.y};
            h8 F2 = {w23.x, w23.x, w23.x, w23.x, w23.x, w23.x, w23.x, w23.x};
            h8 F3 = {w23.y, w23.y, w23.y, w23.y, w23.y, w23.y, w23.y, w23.y};
            h8 a0, a1, a2, a3;
            __builtin_memcpy(&a0, &q[j][0], 16);
            __builtin_memcpy(&a1, &q[j][1], 16);
            __builtin_memcpy(&a2, &q[j][2], 16);
            __builtin_memcpy(&a3, &q[j][3], 16);
            h8 v = a0 * F0 + a1 * F1 + a2 * F2 + a3 * F3;
            uint4 ov;
            __builtin_memcpy(&ov, &v, 16);
            int ccs = cc ^ (p & (NCH - 1));
            *(uint4*)&dst[p * C + ccs * 8] = ov;
        }
    };

    f32x4 acc[4][2];
#pragma unroll
    for (int mt = 0; mt < 4; ++mt)
#pragma unroll
        for (int nt = 0; nt < 2; ++nt) acc[mt][nt] = (f32x4){0.f, 0.f, 0.f, 0.f};

    const ushort* bbase[2];
#pragma unroll
    for (int nt = 0; nt < 2; ++nt)
        bbase[nt] = wt + (size_t)(wv * 32 + nt * 16 + n16) * KP + quad * 8;

    auto mfma_run = [&](const ushort* ab, int kc, int s0, int s1) {
#pragma unroll
        for (int s = s0; s < s1; ++s) {
            h8 av[4], bv[2];
            int ch = (s * 4 + quad) ^ xr;
#pragma unroll
            for (int mt = 0; mt < 4; ++mt)
                av[mt] = *(const h8*)(ab + (mt * 16 + n16) * C + ch * 8);
#pragma unroll
            for (int nt = 0; nt < 2; ++nt)
                bv[nt] = *(const h8*)(bbase[nt] + kc * CPW + s * 32);
#pragma unroll
            for (int mt = 0; mt < 4; ++mt)
#pragma unroll
                for (int nt = 0; nt < 2; ++nt)
                    acc[mt][nt] = __builtin_amdgcn_mfma_f32_16x16x32_f16(
                        av[mt], bv[nt], acc[mt][nt], 0, 0, 0);
        }
    };

    {
        uint4 q[HNIT][4];
        uint2 fw[HNIT];
        issue_loads(0, 0, q, fw);
        interp_write(abuf0, 0, q, fw);
        issue_loads(0, HNIT, q, fw);
        interp_write(abuf0, HNIT, q, fw);
    }
    __syncthreads();

#pragma unroll 1
    for (int kc = 0; kc < 9; ++kc) {
        const ushort* ab = (kc & 1) ? abuf1 : abuf0;
        ushort* dst = (kc & 1) ? abuf0 : abuf1;
        uint4 q[HNIT][4];
        uint2 fw[HNIT];
        if (kc < 8) issue_loads(kc + 1, 0, q, fw);
        __builtin_amdgcn_s_setprio(1);
        mfma_run(ab, kc, 0, SH);
        __builtin_amdgcn_s_setprio(0);
        if (kc < 8) {
            interp_write(dst, 0, q, fw);
            issue_loads(kc + 1, HNIT, q, fw);
        }
        __builtin_amdgcn_s_setprio(1);
        mfma_run(ab, kc, SH, C / 32);
        __builtin_amdgcn_s_setprio(0);
        if (kc < 8) interp_write(dst, HNIT, q, fw);
        __syncthreads();
    }

    // ---- epilogue: transpose via LDS; bn stats (fp32) + raw fp16 NHWC out ----
    float* sm = (float*)smem_raw;
    constexpr int SROW = PIX + 1;
#pragma unroll
    for (int mt = 0; mt < 4; ++mt)
#pragma unroll
        for (int nt = 0; nt < 2; ++nt) {
            int o = wv * 32 + nt * 16 + n16;
            int mb = mt * 16 + quad * 4;
#pragma unroll
            for (int r = 0; r < 4; ++r) sm[o * SROW + mb + r] = acc[mt][nt][r];
        }
    __syncthreads();
    {
        // stats: thread = (o, half), 32 px each, fp32-accurate
        int o = tid >> 1, half = tid & 1;
        const float* sp = sm + o * SROW + half * 32;
        float s = 0.f, qq = 0.f;
#pragma unroll
        for (int i = 0; i < 32; i += 4) {
            float4 v = make_float4(sp[i], sp[i + 1], sp[i + 2], sp[i + 3]);
            s += v.x + v.y + v.z + v.w;
            qq += v.x * v.x + v.y * v.y + v.z * v.z + v.w * v.w;
        }
        s += __shfl_down(s, 1, 64);
        qq += __shfl_down(qq, 1, 64);
        if (half == 0) {
            float* pr = praw + (blockIdx.x & 7) * 256;
            atomicAdd(&pr[o], s);
            atomicAdd(&pr[128 + o], qq);
        }
    }
    {
        // NHWC fp16 raw write: thread = (p = tid>>2, cc4 = tid&3), 32 ch
        int p = tid >> 2, cc4 = tid & 3;
        unsigned ov[16];
#pragma unroll
        for (int j = 0; j < 16; ++j) {
            int c = cc4 * 32 + 2 * j;
            ov[j] = f2h2(sm[c * SROW + p], sm[(c + 1) * SROW + p]);
        }
        uint4* dst = (uint4*)(xout + ((size_t)(m0 + p)) * 64 + cc4 * 16);
        dst[0] = uint4{ov[0], ov[1], ov[2], ov[3]};
        dst[1] = uint4{ov[4], ov[5], ov[6], ov[7]};
        dst[2] = uint4{ov[8], ov[9], ov[10], ov[11]};
        dst[3] = uint4{ov[12], ov[13], ov[14], ov[15]};
    }
}

// ---- deformable conv stage-2: PIX=64 (2 rows x 32 cols) -> block-local
// 2x2 maxpool (R5-proven form) + INLINE bn-normalize on the RAW gather
// (stats finalized in prologue from pr_in replicas). ----
template <int C>
__global__ __launch_bounds__(256, 4) void deform_mfma3p(
    const ushort* __restrict__ xh, const float* __restrict__ dyb,
    const float* __restrict__ dxb, const float* __restrict__ mob,
    const ushort* __restrict__ wt, float* __restrict__ pout,
    float* __restrict__ praw, const float* __restrict__ pr_in) {
    constexpr int PIX = 64;
    constexpr int NCH = C / 8;
    constexpr int NCC = C / 8;
    constexpr int NIT = PIX * NCC / 256;
    constexpr int HNIT = NIT / 2;
    constexpr int SH = (C / 32) / 2 > 0 ? (C / 32) / 2 : 1;
    constexpr int CPW = C + 8;
    constexpr int KP = ((9 * CPW + 31) / 32) * 32;
    constexpr int ABUF = PIX * C;
    constexpr int LOOPB = 2 * ABUF * 2 + PIX * 9 * 4 + PIX * 9 * 8;
    constexpr int EPIB = 128 * (PIX + 1) * 4;
    constexpr int SMEMB = (LOOPB > EPIB ? LOOPB : EPIB) + 512;

    __shared__ __align__(16) char smem_raw[SMEMB];
    ushort* abuf0 = (ushort*)smem_raw;
    ushort* abuf1 = abuf0 + ABUF;
    int* tbl = (int*)(abuf0 + 2 * ABUF);
    unsigned* twl = (unsigned*)(smem_raw + 2 * ABUF * 2 + PIX * 9 * 4);
    unsigned* cst = (unsigned*)(smem_raw + (SMEMB - 512));  // rstd2[64]|nmr2[64]

    // XCD-contiguous swizzle, then bid = b*256 + rp*4 + g
    const int bid = (blockIdx.x & 7) * (gridDim.x >> 3) + (blockIdx.x >> 3);
    const int b = bid >> 8;
    const int rp = (bid >> 2) & 63;
    const int g = bid & 3;
    const int tid = threadIdx.x;
    const int lane = tid & 63, wv = tid >> 6;
    const int n16 = lane & 15, quad = lane >> 4;
    const int xr = n16 & (NCH - 1);

    // stage-1 stats finalize (for inline normalization of the raw gather)
    if (tid < 64) {
        int c0i = 2 * tid, c1i = 2 * tid + 1;
        float s0 = 0.f, q0 = 0.f, s1 = 0.f, q1 = 0.f;
#pragma unroll
        for (int r = 0; r < 8; ++r) {
            s0 += pr_in[r * 256 + c0i];
            q0 += pr_in[r * 256 + 128 + c0i];
            s1 += pr_in[r * 256 + c1i];
            q1 += pr_in[r * 256 + 128 + c1i];
        }
        float m0v = s0 / 65536.f, m1v = s1 / 65536.f;
        float r0 = rsqrtf(q0 / 65536.f - m0v * m0v + 1e-5f);
        float r1 = rsqrtf(q1 / 65536.f - m1v * m1v + 1e-5f);
        cst[tid] = f2h2(r0, r1);
        cst[64 + tid] = f2h2(-m0v * r0, -m1v * r1);
    }

    // pixel p in [0,64): row = 2*rp + (p>>5), col = g*32 + (p&31)
    for (int r = tid; r < PIX * 9; r += 256) {
        int p = r & (PIX - 1), k = r >> 6;
        int row = 2 * rp + (p >> 5), col = g * 32 + (p & 31);
        int oi = ((b * 9 + k) << 14) + (row << 7) + col;
        float py = (float)(row + k / 3 - 1) + dyb[oi];
        float px = (float)(col + k % 3 - 1) + dxb[oi];
        float mv = mob[oi];
        float y0f = floorf(py), x0f = floorf(px);
        float wy = py - y0f, wx = px - x0f;
        int y0 = (int)y0f, x0 = (int)x0f;
        int y1 = y0 + 1, x1 = x0 + 1;
        float f00 = (1.f - wy) * (1.f - wx) *
                    (((unsigned)y0 < 128u && (unsigned)x0 < 128u) ? mv : 0.f);
        float f01 = (1.f - wy) * wx *
                    (((unsigned)y0 < 128u && (unsigned)x1 < 128u) ? mv : 0.f);
        float f10 = wy * (1.f - wx) *
                    (((unsigned)y1 < 128u && (unsigned)x0 < 128u) ? mv : 0.f);
        float f11 = wy * wx *
                    (((unsigned)y1 < 128u && (unsigned)x1 < 128u) ? mv : 0.f);
        int cy0 = min(max(y0, 0), 127), cy1 = min(max(y1, 0), 127);
        int cx0 = min(max(x0, 0), 127), cx1 = min(max(x1, 0), 127);
        int base00 = (((b << 14) + (cy0 << 7) + cx0)) * C;
        int flags = ((cy1 != cy0) ? 2 : 0) | ((cx1 != cx0) ? 1 : 0);
        int s = p * 9 + k;
        tbl[s] = base00 | flags;
        twl[2 * s] = f2h2(f00, f01);
        twl[2 * s + 1] = f2h2(f10, f11);
    }
    __syncthreads();

    // per-thread channel-norm constants (cc = tid % NCC is loop-invariant)
    const int ccf = tid & (NCC - 1);
    const h8 Rv = *(const h8*)&cst[ccf * 4];
    const h8 Nv = *(const h8*)&cst[64 + ccf * 4];

    auto issue_loads = [&](int kc, int it0, uint4 (&q)[HNIT][4],
                           uint2 (&fw)[HNIT]) {
#pragma unroll
        for (int j = 0; j < HNIT; ++j) {
            int e = (it0 + j) * 256 + tid;
            int p = e / NCC, cc = e % NCC;
            int s = p * 9 + kc;
            int ent = tbl[s];
            fw[j] = *(const uint2*)&twl[2 * s];
            int base = ent & ~3;
            int dxo = (ent & 1) ? C : 0;
            int dyo = (ent & 2) ? (C << 7) : 0;
            const ushort* pp = xh + (size_t)base + cc * 8;
            q[j][0] = *(const uint4*)(pp);
            q[j][1] = *(const uint4*)(pp + dxo);
            q[j][2] = *(const uint4*)(pp + dyo);
            q[j][3] = *(const uint4*)(pp + dyo + dxo);
        }
    };
    auto interp_write = [&](ushort* dst, int it0, uint4 (&q)[HNIT][4],
                            uint2 (&fw)[HNIT]) {
#pragma unroll
        for (int j = 0; j < HNIT; ++j) {
            int e = (it0 + j) * 256 + tid;
            int p = e / NCC, cc = e % NCC;
            h2 w01, w23;
            __builtin_memcpy(&w01, &fw[j].x, 4);
            __builtin_memcpy(&w23, &fw[j].y, 4);
            h8 F0 = {w01.x, w01.x, w01.x, w01.x, w01.x, w01.x, w01.x, w01.x};
            h8 F1 = {w01.y, w01.y, w01.y, w01.y, w01.y, w01.y, w01.y, w01.y};
            h8 F2 = {w23.x, w23.x, w23.x, w23.x, w23.x, w23.x, w23.x, w23.x};
            h8 F3 = {w23.y, w23.y, w23.y, w23.y, w23.y, w23.y, w23.y, w23.y};
            h8 a0, a1, a2, a3;
            __builtin_memcpy(&a0, &q[j][0], 16);
            __builtin_memcpy(&a1, &q[j][1], 16);
            __builtin_memcpy(&a2, &q[j][2], 16);
            __builtin_memcpy(&a3, &q[j][3], 16);
            a0 = nrelu8(a0, Rv, Nv);
            a1 = nrelu8(a1, Rv, Nv);
            a2 = nrelu8(a2, Rv, Nv);
            a3 = nrelu8(a3, Rv, Nv);
            h8 v = a0 * F0 + a1 * F1 + a2 * F2 + a3 * F3;
            uint4 ov;
            __builtin_memcpy(&ov, &v, 16);
            int ccs = cc ^ (p & (NCH - 1));
            *(uint4*)&dst[p * C + ccs * 8] = ov;
        }
    };

    f32x4 acc[4][2];
#pragma unroll
    for (int mt = 0; mt < 4; ++mt)
#pragma unroll
        for (int nt = 0; nt < 2; ++nt) acc[mt][nt] = (f32x4){0.f, 0.f, 0.f, 0.f};

    const ushort* bbase[2];
#pragma unroll
    for (int nt = 0; nt < 2; ++nt)
        bbase[nt] = wt + (size_t)(wv * 32 + nt * 16 + n16) * KP + quad * 8;

    auto mfma_run = [&](const ushort* ab, int kc, int s0, int s1) {
#pragma unroll
        for (int s = s0; s < s1; ++s) {
            h8 av[4], bv[2];
            int ch = (s * 4 + quad) ^ xr;
#pragma unroll
            for (int mt = 0; mt < 4; ++mt)
                av[mt] = *(const h8*)(ab + (mt * 16 + n16) * C + ch * 8);
#pragma unroll
            for (int nt = 0; nt < 2; ++nt)
                bv[nt] = *(const h8*)(bbase[nt] + kc * CPW + s * 32);
#pragma unroll
            for (int mt = 0; mt < 4; ++mt)
#pragma unroll
                for (int nt = 0; nt < 2; ++nt)
                    acc[mt][nt] = __builtin_amdgcn_mfma_f32_16x16x32_f16(
                        av[mt], bv[nt], acc[mt][nt], 0, 0, 0);
        }
    };

    {
        uint4 q[HNIT][4];
        uint2 fw[HNIT];
        issue_loads(0, 0, q, fw);
        interp_write(abuf0, 0, q, fw);
        issue_loads(0, HNIT, q, fw);
        interp_write(abuf0, HNIT, q, fw);
    }
    __syncthreads();

#pragma unroll 1
    for (int kc = 0; kc < 9; ++kc) {
        const ushort* ab = (kc & 1) ? abuf1 : abuf0;
        ushort* dst = (kc & 1) ? abuf0 : abuf1;
        uint4 q[HNIT][4];
        uint2 fw[HNIT];
        if (kc < 8) issue_loads(kc + 1, 0, q, fw);
        __builtin_amdgcn_s_setprio(1);
        mfma_run(ab, kc, 0, SH);
        __builtin_amdgcn_s_setprio(0);
        if (kc < 8) {
            interp_write(dst, 0, q, fw);
            issue_loads(kc + 1, HNIT, q, fw);
        }
        __builtin_amdgcn_s_setprio(1);
        mfma_run(ab, kc, SH, C / 32);
        __builtin_amdgcn_s_setprio(0);
        if (kc < 8) interp_write(dst, HNIT, q, fw);
        __syncthreads();
    }

    // ---- epilogue: stats from full-res tile + block-local 2x2 pool ----
    float* sm = (float*)smem_raw;
    constexpr int SROW = PIX + 1;
#pragma unroll
    for (int mt = 0; mt < 4; ++mt)
#pragma unroll
        for (int nt = 0; nt < 2; ++nt) {
            int o = wv * 32 + nt * 16 + n16;
            int mb = mt * 16 + quad * 4;
#pragma unroll
            for (int r = 0; r < 4; ++r) sm[o * SROW + mb + r] = acc[mt][nt][r];
        }
    __syncthreads();
    {
        int o = tid >> 1, half = tid & 1;
        const float* so = sm + o * SROW;
        const float* sp = so + half * 32;
        float s = 0.f, qq = 0.f;
#pragma unroll
        for (int i = 0; i < 32; i += 4) {
            float4 v = make_float4(sp[i], sp[i + 1], sp[i + 2], sp[i + 3]);
            s += v.x + v.y + v.z + v.w;
            qq += v.x * v.x + v.y * v.y + v.z * v.z + v.w * v.w;
        }
        s += __shfl_down(s, 1, 64);
        qq += __shfl_down(qq, 1, 64);
        if (half == 0) {
            float* pr = praw + (blockIdx.x & 7) * 256;
            atomicAdd(&pr[o], s);
            atomicAdd(&pr[128 + o], qq);
        }
        // pool: rows are px [0,32) and [32,64); pooled cols pc = half*8 + i
        float4 pv0, pv1;
#pragma unroll
        for (int i = 0; i < 8; ++i) {
            int pc = half * 8 + i;
            float m0v = fmaxf(so[2 * pc], so[2 * pc + 1]);
            float m1v = fmaxf(so[32 + 2 * pc], so[32 + 2 * pc + 1]);
            float m = fmaxf(m0v, m1v);
            if (i < 4) ((float*)&pv0)[i] = m;
            else ((float*)&pv1)[i - 4] = m;
        }
        float* dp = pout + (((size_t)(b * 128 + o)) << 12) + rp * 64 + g * 16 +
                    half * 8;
        *(float4*)(dp) = pv0;
        *(float4*)(dp + 4) = pv1;
    }
}

// ---- pooled normalize: out = relu((pout - mean) * rstd) ----
__global__ __launch_bounds__(256) void pool_norm(const float* __restrict__ pout,
                                                 const float* __restrict__ praw,
                                                 float* __restrict__ out) {
    __shared__ float lstats[256];
    if (threadIdx.x < 128) {
        int c = threadIdx.x;
        float s = 0.f, q = 0.f;
#pragma unroll
        for (int r = 0; r < 8; ++r) {
            s += praw[r * 256 + c];
            q += praw[r * 256 + 128 + c];
        }
        float mean = s / 65536.f;
        float var = q / 65536.f - mean * mean;
        lstats[c] = mean;
        lstats[128 + c] = rsqrtf(var + 1e-5f);
    }
    __syncthreads();
    int i = blockIdx.x * 256 + threadIdx.x;  // float4 index, total 524288
    int c = (i >> 10) & 127;
    float mean = lstats[c], rstd = lstats[128 + c];
    float4 v = ((const float4*)pout)[i];
    v.x = fmaxf(0.f, (v.x - mean) * rstd);
    v.y = fmaxf(0.f, (v.y - mean) * rstd);
    v.z = fmaxf(0.f, (v.z - mean) * rstd);
    v.w = fmaxf(0.f, (v.w - mean) * rstd);
    ((float4*)out)[i] = v;
}

extern "C" void kernel_launch(void* const* d_in, const int* in_sizes, int n_in,
                              void* d_out, int out_size, void* d_ws,
                              size_t ws_size, hipStream_t stream) {
    (void)in_sizes;
    (void)n_in;
    (void)out_size;
    (void)ws_size;
    const float* x = (const float*)d_in[0];
    const float* w_off1 = (const float*)d_in[1];
    const float* b_off1 = (const float*)d_in[2];
    const float* w_mod1 = (const float*)d_in[3];
    const float* b_mod1 = (const float*)d_in[4];
    const float* w1 = (const float*)d_in[5];
    const float* w_off2 = (const float*)d_in[6];
    const float* b_off2 = (const float*)d_in[7];
    const float* w_mod2 = (const float*)d_in[8];
    const float* b_mod2 = (const float*)d_in[9];
    const float* w2 = (const float*)d_in[10];
    float* out = (float*)d_out;
    float* ws = (float*)d_ws;

    // KP1 = 672 (C=64, CP=72), KP2 = 1248 (C=128, CP=136)
    ushort* Wt1 = (ushort*)ws;                            // 86016 ush = 43008 f
    ushort* Wt2 = (ushort*)(ws + 43008);                  // 159744 ush = 79872 f
    ushort* Wo1 = (ushort*)(ws + 43008 + 79872);          // need 18432 ush
    ushort* Wo2 = (ushort*)(ws + 43008 + 79872 + 16384);  // need 36864 ush
    float* dyb = ws + 172032;
    float* dxb = dyb + 589824;
    float* mob = dxb + 589824;
    float* hbuf = mob + 589824;      // h1 RAW fp16 NHWC (lives through stage 2)
    float* xhf = hbuf + 8388608;     // 2097152 f: x as NHWC fp16
    float* h1hf = xhf + 2097152;     // 4194304 f: now pooled raw max (2M used)
    float* praw1 = h1hf + 4194304;   // 2048 (8 replicas x 256) stage-1 stats
    float* praw2 = praw1 + 2048;     // 2048 stage-2 stats
    ushort* xh = (ushort*)xhf;
    ushort* hb = (ushort*)hbuf;

    prep_weights<<<1176, 256, 0, stream>>>(w1, w2, w_off1, w_mod1, w_off2,
                                           w_mod2, Wt1, Wt2, Wo1, Wo2);

    // ---- stage 1 ----
    nhwc_cvt<64><<<1024, 256, 0, stream>>>(x, (unsigned*)xh);
    offmod_nhwc<64, false><<<1024, 256, 0, stream>>>(
        xh, Wo1, b_off1, b_mod1, dyb, dxb, mob, praw1, praw1);
    deform_mfma3<64><<<1024, 256, 0, stream>>>(xh, dyb, dxb, mob, Wt1,
                                               (unsigned*)hbuf, praw1);

    // ---- stage 2 (bn of h1 fused inline: consumers read RAW hbuf + praw1) ----
    offmod_nhwc<128, true><<<1024, 256, 0, stream>>>(
        hb, Wo2, b_off2, b_mod2, dyb, dxb, mob, praw2, praw1);
    deform_mfma3p<128><<<1024, 256, 0, stream>>>(hb, dyb, dxb, mob, Wt2, h1hf,
                                                 praw2, praw1);
    pool_norm<<<2048, 256, 0, stream>>>(h1hf, praw2, out);
}

// Round 10
// 247.599 us; speedup vs baseline: 1.2094x; 1.0120x over previous
//
#include <hip/hip_runtime.h>
#include <math.h>

#define HH 128
#define WW 128
#define HWSZ 16384

typedef __attribute__((ext_vector_type(8))) _Float16 h8;
typedef __attribute__((ext_vector_type(2))) _Float16 h2;
typedef __attribute__((ext_vector_type(4))) float f32x4;
typedef __attribute__((ext_vector_type(2))) float f32x2;
typedef unsigned short ushort;

// fp16 conversion helpers (RNE via scalar cast)
__device__ __forceinline__ ushort f2h(float f) {
    _Float16 h = (_Float16)f;
    ushort u;
    __builtin_memcpy(&u, &h, 2);
    return u;
}
// pack two floats -> packed fp16 dword (lo in [15:0], hi in [31:16])
__device__ __forceinline__ unsigned f2h2(float lo, float hi) {
    h2 r;
    r.x = (_Float16)lo;
    r.y = (_Float16)hi;
    unsigned u;
    __builtin_memcpy(&u, &r, 4);
    return u;
}
// unpack 2 packed fp16 (one dword) to float2
__device__ __forceinline__ f32x2 unpk_h2(unsigned u) {
    h2 h;
    __builtin_memcpy(&h, &u, 4);
    return (f32x2){(float)h.x, (float)h.y};
}
// fused per-channel normalize + relu on 8 packed fp16: max(a*R + N, 0)
__device__ __forceinline__ h8 nrelu8(h8 a, h8 R, h8 N) {
    h8 t = a * R + N;
#if __has_builtin(__builtin_elementwise_max)
    h8 z = {};
    return __builtin_elementwise_max(t, z);
#else
    h8 r;
#pragma unroll
    for (int i = 0; i < 8; ++i)
        r[i] = t[i] > (_Float16)0 ? t[i] : (_Float16)0;
    return r;
#endif
}

// ---- merged: NCHW fp32 -> NHWC fp16 converter (blocks 0..1023) +
// weight prep wpad1|wpad2|woff1|woff2 (blocks 1024..2199) ----
template <int C>
__global__ __launch_bounds__(256) void cvt_prep(
    const float* __restrict__ xin, unsigned* __restrict__ xout,
    const float* __restrict__ w1, const float* __restrict__ w2,
    const float* __restrict__ w_off1, const float* __restrict__ w_mod1,
    const float* __restrict__ w_off2, const float* __restrict__ w_mod2,
    ushort* __restrict__ Wt1, ushort* __restrict__ Wt2,
    ushort* __restrict__ Wo1, ushort* __restrict__ Wo2) {
    __shared__ float tile[64][C + 1];
    const int gb = blockIdx.x;
    const int tid = threadIdx.x;
    if (gb >= 1024) {
        int bid = gb - 1024;
        if (bid < 336) {
            int i = bid * 256 + tid;
            int o = i / 672, kq = i % 672;
            int k = kq / 72, c = kq % 72;
            float v = (k < 9 && c < 64) ? w1[(o * 64 + c) * 9 + k] : 0.f;
            Wt1[i] = f2h(v);
        } else if (bid < 960) {
            int i = (bid - 336) * 256 + tid;
            int o = i / 1248, kq = i % 1248;
            int k = kq / 136, c = kq % 136;
            float v = (k < 9 && c < 128) ? w2[(o * 128 + c) * 9 + k] : 0.f;
            Wt2[i] = f2h(v);
        } else if (bid < 1032) {
            int i = (bid - 960) * 256 + tid;  // < 32*576
            int o = i / 576, kap = i % 576;
            int k = kap / 64, c = kap % 64;
            float v = 0.f;
            if (o < 18) v = w_off1[(o * 64 + c) * 9 + k];
            else if (o < 27) v = w_mod1[((o - 18) * 64 + c) * 9 + k];
            Wo1[i] = f2h(v);
        } else {
            int i = (bid - 1032) * 256 + tid;  // < 32*1152
            int o = i / 1152, kap = i % 1152;
            int k = kap / 128, c = kap % 128;
            float v = 0.f;
            if (o < 18) v = w_off2[(o * 128 + c) * 9 + k];
            else if (o < 27) v = w_mod2[((o - 18) * 128 + c) * 9 + k];
            Wo2[i] = f2h(v);
        }
        return;
    }
    const int m0 = gb * 64;
    const int b = m0 >> 14;
    const int hw0 = m0 & 16383;
    const int pr = tid & 63, cr = tid >> 6;
#pragma unroll
    for (int it = 0; it < C / 4; ++it) {
        int c = it * 4 + cr;
        tile[pr][c] = xin[(((size_t)(b * C + c)) << 14) + hw0 + pr];
    }
    __syncthreads();
    constexpr int CH = C / 2;
#pragma unroll
    for (int it = 0; it < 64 * CH / 256; ++it) {
        int slot = it * 256 + tid;
        int p = slot / CH, cc = slot % CH;
        xout[(size_t)(m0 + p) * CH + cc] =
            f2h2(tile[p][2 * cc], tile[p][2 * cc + 1]);
    }
}

// ---- offset/mod conv: NHWC-fp16 direct A-fragment MFMA GEMM ----
// NORM: read RAW input + inline bn (stats from pr_in replicas).
// also zeroes the praw_out replicas for the following deform.
// XCD-contiguous bid swizzle for neighbor-row L2 locality.
template <int C, bool NORM>
__global__ __launch_bounds__(256) void offmod_nhwc(
    const ushort* __restrict__ xh, const ushort* __restrict__ wt,
    const float* __restrict__ b_off, const float* __restrict__ b_mod,
    float* __restrict__ dyb, float* __restrict__ dxb, float* __restrict__ mob,
    float* __restrict__ praw_out, const float* __restrict__ pr_in) {
    constexpr int K = C * 9;
    __shared__ unsigned cstat[128];  // rstd2[64] | nmr2[64]
    if (blockIdx.x < 8) praw_out[blockIdx.x * 256 + threadIdx.x] = 0.f;
    const int bid = (blockIdx.x & 7) * (gridDim.x >> 3) + (blockIdx.x >> 3);
    const int m0 = bid * 64;
    const int b = m0 >> 14;
    const int hw0 = m0 & 16383;
    const int h = hw0 >> 7;
    const int w0 = hw0 & 127;
    const int tid = threadIdx.x;
    const int lane = tid & 63, wv = tid >> 6;
    const int n16 = lane & 15, quad = lane >> 4;
    const int p = wv * 16 + n16;
    const int w = w0 + p;

    if (NORM) {
        if (tid < 64) {
            int c0i = 2 * tid, c1i = 2 * tid + 1;
            float s0 = 0.f, q0 = 0.f, s1 = 0.f, q1 = 0.f;
#pragma unroll
            for (int r = 0; r < 8; ++r) {
                s0 += pr_in[r * 256 + c0i];
                q0 += pr_in[r * 256 + 128 + c0i];
                s1 += pr_in[r * 256 + c1i];
                q1 += pr_in[r * 256 + 128 + c1i];
            }
            float m0v = s0 / 65536.f, m1v = s1 / 65536.f;
            float r0 = rsqrtf(q0 / 65536.f - m0v * m0v + 1e-5f);
            float r1 = rsqrtf(q1 / 65536.f - m1v * m1v + 1e-5f);
            cstat[tid] = f2h2(r0, r1);
            cstat[64 + tid] = f2h2(-m0v * r0, -m1v * r1);
        }
        __syncthreads();
    }

    h8 Rv[4], Nv[4];
    if (NORM) {
#pragma unroll
        for (int si = 0; si < 4; ++si) {
            int db = si * 16 + quad * 4;
            Rv[si] = *(const h8*)&cstat[db];
            Nv[si] = *(const h8*)&cstat[64 + db];
        }
    }

    int tbase[9];
    bool tval[9];
#pragma unroll
    for (int k = 0; k < 9; ++k) {
        int yy = h + k / 3 - 1, xx = w + k % 3 - 1;
        tval[k] = ((unsigned)yy < 128u) && ((unsigned)xx < 128u);
        int cy = min(max(yy, 0), 127), cx = min(max(xx, 0), 127);
        tbase[k] = ((b << 14) + (cy << 7) + cx) * C + quad * 8;
    }

    f32x4 acc[2];
    acc[0] = (f32x4){0.f, 0.f, 0.f, 0.f};
    acc[1] = (f32x4){0.f, 0.f, 0.f, 0.f};

    const ushort* b0p = wt + (size_t)n16 * K + quad * 8;
    const ushort* b1p = wt + (size_t)(16 + n16) * K + quad * 8;

#pragma unroll
    for (int s = 0; s < K / 32; ++s) {
        const int k = (s * 32) / C;
        const int c0 = (s * 32) % C;
        h8 a = {0, 0, 0, 0, 0, 0, 0, 0};
        if (tval[k]) {
            a = *(const h8*)(xh + (size_t)tbase[k] + c0);
            if (NORM) {
                const int si = s & ((C / 32) - 1);
                a = nrelu8(a, Rv[si], Nv[si]);
            }
        }
        const h8 bv0 = *(const h8*)(b0p + s * 32);
        const h8 bv1 = *(const h8*)(b1p + s * 32);
        acc[0] = __builtin_amdgcn_mfma_f32_16x16x32_f16(a, bv0, acc[0], 0, 0, 0);
        acc[1] = __builtin_amdgcn_mfma_f32_16x16x32_f16(a, bv1, acc[1], 0, 0, 0);
    }

    __shared__ float sm[32 * 65];
#pragma unroll
    for (int nt = 0; nt < 2; ++nt) {
        int n = nt * 16 + n16;
        int pb = wv * 16 + quad * 4;
#pragma unroll
        for (int r = 0; r < 4; ++r) sm[n * 65 + pb + r] = acc[nt][r];
    }
    __syncthreads();
    {
        int n = tid >> 3, i8 = tid & 7;
        if (n < 27) {
            const float* sp = sm + n * 65 + i8 * 8;
            int px = hw0 + i8 * 8;
            if (n < 18) {
                int k = n >> 1;
                float bias = b_off[n];
                float* dst =
                    ((n & 1) ? dxb : dyb) + (((size_t)(b * 9 + k)) << 14) + px;
#pragma unroll
                for (int j = 0; j < 8; j += 4) {
                    float4 v = make_float4(sp[j] + bias, sp[j + 1] + bias,
                                           sp[j + 2] + bias, sp[j + 3] + bias);
                    *(float4*)(dst + j) = v;
                }
            } else {
                float bias = b_mod[n - 18];
                float* dst = mob + (((size_t)(b * 9 + (n - 18))) << 14) + px;
#pragma unroll
                for (int j = 0; j < 8; j += 4) {
                    float4 v;
                    v.x = 2.f / (1.f + expf(-(sp[j] + bias)));
                    v.y = 2.f / (1.f + expf(-(sp[j + 1] + bias)));
                    v.z = 2.f / (1.f + expf(-(sp[j + 2] + bias)));
                    v.w = 2.f / (1.f + expf(-(sp[j + 3] + bias)));
                    *(float4*)(dst + j) = v;
                }
            }
        }
    }
}

// ---- deformable conv v3 (stage 1): PIX=64, XOR-swizzled LDS A-buffer,
// packed gather table, HALF-batch prefetch (spill-free: q[2][4] = 32 VGPR),
// XCD-contiguous bid swizzle, setprio on MFMA halves. (R5-proven form) ----
template <int C>
__global__ __launch_bounds__(256, 4) void deform_mfma3(
    const ushort* __restrict__ xh, const float* __restrict__ dyb,
    const float* __restrict__ dxb, const float* __restrict__ mob,
    const ushort* __restrict__ wt, unsigned* __restrict__ xout,
    float* __restrict__ praw) {
    constexpr int PIX = 64;
    constexpr int NCH = C / 8;   // 16B chunks per row
    constexpr int NCC = C / 8;
    constexpr int NIT = PIX * NCC / 256;
    constexpr int HNIT = NIT / 2;
    constexpr int SH = (C / 32) / 2 > 0 ? (C / 32) / 2 : 1;
    constexpr int CPW = C + 8;
    constexpr int KP = ((9 * CPW + 31) / 32) * 32;
    constexpr int ABUF = PIX * C;  // ushorts, no pad (XOR swizzle instead)
    constexpr int LOOPB = 2 * ABUF * 2 + PIX * 9 * 4 + PIX * 9 * 8;
    constexpr int EPIB = 128 * (PIX + 1) * 4;
    constexpr int SMEMB = LOOPB > EPIB ? LOOPB : EPIB;

    __shared__ __align__(16) char smem_raw[SMEMB];
    ushort* abuf0 = (ushort*)smem_raw;
    ushort* abuf1 = abuf0 + ABUF;
    int* tbl = (int*)(abuf0 + 2 * ABUF);
    unsigned* twl = (unsigned*)(smem_raw + 2 * ABUF * 2 + PIX * 9 * 4);

    // XCD-contiguous swizzle: each XCD owns a contiguous 1/8 of the image
    const int bid = (blockIdx.x & 7) * (gridDim.x >> 3) + (blockIdx.x >> 3);
    const int m0 = bid * PIX;
    const int b = m0 >> 14;
    const int hw0 = m0 & 16383;
    const int h = hw0 >> 7, w0 = hw0 & 127;
    const int tid = threadIdx.x;
    const int lane = tid & 63, wv = tid >> 6;
    const int n16 = lane & 15, quad = lane >> 4;
    const int xr = n16 & (NCH - 1);

    for (int r = tid; r < PIX * 9; r += 256) {
        int p = r & (PIX - 1), k = r >> 6;
        int oi = ((b * 9 + k) << 14) + hw0 + p;
        float py = (float)(h + k / 3 - 1) + dyb[oi];
        float px = (float)(w0 + p + k % 3 - 1) + dxb[oi];
        float mv = mob[oi];
        float y0f = floorf(py), x0f = floorf(px);
        float wy = py - y0f, wx = px - x0f;
        int y0 = (int)y0f, x0 = (int)x0f;
        int y1 = y0 + 1, x1 = x0 + 1;
        float f00 = (1.f - wy) * (1.f - wx) *
                    (((unsigned)y0 < 128u && (unsigned)x0 < 128u) ? mv : 0.f);
        float f01 = (1.f - wy) * wx *
                    (((unsigned)y0 < 128u && (unsigned)x1 < 128u) ? mv : 0.f);
        float f10 = wy * (1.f - wx) *
                    (((unsigned)y1 < 128u && (unsigned)x0 < 128u) ? mv : 0.f);
        float f11 = wy * wx *
                    (((unsigned)y1 < 128u && (unsigned)x1 < 128u) ? mv : 0.f);
        int cy0 = min(max(y0, 0), 127), cy1 = min(max(y1, 0), 127);
        int cx0 = min(max(x0, 0), 127), cx1 = min(max(x1, 0), 127);
        int base00 = (((b << 14) + (cy0 << 7) + cx0)) * C;
        int flags = ((cy1 != cy0) ? 2 : 0) | ((cx1 != cx0) ? 1 : 0);
        int s = p * 9 + k;
        tbl[s] = base00 | flags;
        twl[2 * s] = f2h2(f00, f01);
        twl[2 * s + 1] = f2h2(f10, f11);
    }
    __syncthreads();

    auto issue_loads = [&](int kc, int it0, uint4 (&q)[HNIT][4],
                           uint2 (&fw)[HNIT]) {
#pragma unroll
        for (int j = 0; j < HNIT; ++j) {
            int e = (it0 + j) * 256 + tid;
            int p = e / NCC, cc = e % NCC;
            int s = p * 9 + kc;
            int ent = tbl[s];
            fw[j] = *(const uint2*)&twl[2 * s];
            int base = ent & ~3;
            int dxo = (ent & 1) ? C : 0;
            int dyo = (ent & 2) ? (C << 7) : 0;
            const ushort* pp = xh + (size_t)base + cc * 8;
            q[j][0] = *(const uint4*)(pp);
            q[j][1] = *(const uint4*)(pp + dxo);
            q[j][2] = *(const uint4*)(pp + dyo);
            q[j][3] = *(const uint4*)(pp + dyo + dxo);
        }
    };
    auto interp_write = [&](ushort* dst, int it0, uint4 (&q)[HNIT][4],
                            uint2 (&fw)[HNIT]) {
#pragma unroll
        for (int j = 0; j < HNIT; ++j) {
            int e = (it0 + j) * 256 + tid;
            int p = e / NCC, cc = e % NCC;
            h2 w01, w23;
            __builtin_memcpy(&w01, &fw[j].x, 4);
            __builtin_memcpy(&w23, &fw[j].y, 4);
            h8 F0 = {w01.x, w01.x, w01.x, w01.x, w01.x, w01.x, w01.x, w01.x};
            h8 F1 = {w01.y, w01.y, w01.y, w01.y, w01.y, w01.y, w01.y, w01.y};
            h8 F2 = {w23.x, w23.x, w23.x, w23.x, w23.x, w23.x, w23.x, w23.x};
            h8 F3 = {w23.y, w23.y, w23.y, w23.y, w23.y, w23.y, w23.y, w23.y};
            h8 a0, a1, a2, a3;
            __builtin_memcpy(&a0, &q[j][0], 16);
            __builtin_memcpy(&a1, &q[j][1], 16);
            __builtin_memcpy(&a2, &q[j][2], 16);
            __builtin_memcpy(&a3, &q[j][3], 16);
            h8 v = a0 * F0 + a1 * F1 + a2 * F2 + a3 * F3;
            uint4 ov;
            __builtin_memcpy(&ov, &v, 16);
            int ccs = cc ^ (p & (NCH - 1));
            *(uint4*)&dst[p * C + ccs * 8] = ov;
        }
    };

    f32x4 acc[4][2];
#pragma unroll
    for (int mt = 0; mt < 4; ++mt)
#pragma unroll
        for (int nt = 0; nt < 2; ++nt) acc[mt][nt] = (f32x4){0.f, 0.f, 0.f, 0.f};

    const ushort* bbase[2];
#pragma unroll
    for (int nt = 0; nt < 2; ++nt)
        bbase[nt] = wt + (size_t)(wv * 32 + nt * 16 + n16) * KP + quad * 8;

    auto mfma_run = [&](const ushort* ab, int kc, int s0, int s1) {
#pragma unroll
        for (int s = s0; s < s1; ++s) {
            h8 av[4], bv[2];
            int ch = (s * 4 + quad) ^ xr;
#pragma unroll
            for (int mt = 0; mt < 4; ++mt)
                av[mt] = *(const h8*)(ab + (mt * 16 + n16) * C + ch * 8);
#pragma unroll
            for (int nt = 0; nt < 2; ++nt)
                bv[nt] = *(const h8*)(bbase[nt] + kc * CPW + s * 32);
#pragma unroll
            for (int mt = 0; mt < 4; ++mt)
#pragma unroll
                for (int nt = 0; nt < 2; ++nt)
                    acc[mt][nt] = __builtin_amdgcn_mfma_f32_16x16x32_f16(
                        av[mt], bv[nt], acc[mt][nt], 0, 0, 0);
        }
    };

    {
        uint4 q[HNIT][4];
        uint2 fw[HNIT];
        issue_loads(0, 0, q, fw);
        interp_write(abuf0, 0, q, fw);
        issue_loads(0, HNIT, q, fw);
        interp_write(abuf0, HNIT, q, fw);
    }
    __syncthreads();

#pragma unroll 1
    for (int kc = 0; kc < 9; ++kc) {
        const ushort* ab = (kc & 1) ? abuf1 : abuf0;
        ushort* dst = (kc & 1) ? abuf0 : abuf1;
        uint4 q[HNIT][4];
        uint2 fw[HNIT];
        if (kc < 8) issue_loads(kc + 1, 0, q, fw);
        __builtin_amdgcn_s_setprio(1);
        mfma_run(ab, kc, 0, SH);
        __builtin_amdgcn_s_setprio(0);
        if (kc < 8) {
            interp_write(dst, 0, q, fw);
            issue_loads(kc + 1, HNIT, q, fw);
        }
        __builtin_amdgcn_s_setprio(1);
        mfma_run(ab, kc, SH, C / 32);
        __builtin_amdgcn_s_setprio(0);
        if (kc < 8) interp_write(dst, HNIT, q, fw);
        __syncthreads();
    }

    // ---- epilogue: transpose via LDS; bn stats (fp32) + raw fp16 NHWC out ----
    float* sm = (float*)smem_raw;
    constexpr int SROW = PIX + 1;
#pragma unroll
    for (int mt = 0; mt < 4; ++mt)
#pragma unroll
        for (int nt = 0; nt < 2; ++nt) {
            int o = wv * 32 + nt * 16 + n16;
            int mb = mt * 16 + quad * 4;
#pragma unroll
            for (int r = 0; r < 4; ++r) sm[o * SROW + mb + r] = acc[mt][nt][r];
        }
    __syncthreads();
    {
        // stats: thread = (o, half), 32 px each, fp32-accurate
        int o = tid >> 1, half = tid & 1;
        const float* sp = sm + o * SROW + half * 32;
        float s = 0.f, qq = 0.f;
#pragma unroll
        for (int i = 0; i < 32; i += 4) {
            float4 v = make_float4(sp[i], sp[i + 1], sp[i + 2], sp[i + 3]);
            s += v.x + v.y + v.z + v.w;
            qq += v.x * v.x + v.y * v.y + v.z * v.z + v.w * v.w;
        }
        s += __shfl_down(s, 1, 64);
        qq += __shfl_down(qq, 1, 64);
        if (half == 0) {
            float* pr = praw + (blockIdx.x & 7) * 256;
            atomicAdd(&pr[o], s);
            atomicAdd(&pr[128 + o], qq);
        }
    }
    {
        // NHWC fp16 raw write: thread = (p = tid>>2, cc4 = tid&3), 32 ch
        int p = tid >> 2, cc4 = tid & 3;
        unsigned ov[16];
#pragma unroll
        for (int j = 0; j < 16; ++j) {
            int c = cc4 * 32 + 2 * j;
            ov[j] = f2h2(sm[c * SROW + p], sm[(c + 1) * SROW + p]);
        }
        uint4* dst = (uint4*)(xout + ((size_t)(m0 + p)) * 64 + cc4 * 16);
        dst[0] = uint4{ov[0], ov[1], ov[2], ov[3]};
        dst[1] = uint4{ov[4], ov[5], ov[6], ov[7]};
        dst[2] = uint4{ov[8], ov[9], ov[10], ov[11]};
        dst[3] = uint4{ov[12], ov[13], ov[14], ov[15]};
    }
}

// ---- deformable conv stage-2: PIX=64 (2 rows x 32 cols) -> block-local
// 2x2 maxpool (R5-proven form) + INLINE bn-normalize on the RAW gather
// (stats finalized in prologue from pr_in replicas). ----
template <int C>
__global__ __launch_bounds__(256, 4) void deform_mfma3p(
    const ushort* __restrict__ xh, const float* __restrict__ dyb,
    const float* __restrict__ dxb, const float* __restrict__ mob,
    const ushort* __restrict__ wt, float* __restrict__ pout,
    float* __restrict__ praw, const float* __restrict__ pr_in) {
    constexpr int PIX = 64;
    constexpr int NCH = C / 8;
    constexpr int NCC = C / 8;
    constexpr int NIT = PIX * NCC / 256;
    constexpr int HNIT = NIT / 2;
    constexpr int SH = (C / 32) / 2 > 0 ? (C / 32) / 2 : 1;
    constexpr int CPW = C + 8;
    constexpr int KP = ((9 * CPW + 31) / 32) * 32;
    constexpr int ABUF = PIX * C;
    constexpr int LOOPB = 2 * ABUF * 2 + PIX * 9 * 4 + PIX * 9 * 8;
    constexpr int EPIB = 128 * (PIX + 1) * 4;
    constexpr int SMEMB = (LOOPB > EPIB ? LOOPB : EPIB) + 512;

    __shared__ __align__(16) char smem_raw[SMEMB];
    ushort* abuf0 = (ushort*)smem_raw;
    ushort* abuf1 = abuf0 + ABUF;
    int* tbl = (int*)(abuf0 + 2 * ABUF);
    unsigned* twl = (unsigned*)(smem_raw + 2 * ABUF * 2 + PIX * 9 * 4);
    unsigned* cst = (unsigned*)(smem_raw + (SMEMB - 512));  // rstd2[64]|nmr2[64]

    // XCD-contiguous swizzle, then bid = b*256 + rp*4 + g
    const int bid = (blockIdx.x & 7) * (gridDim.x >> 3) + (blockIdx.x >> 3);
    const int b = bid >> 8;
    const int rp = (bid >> 2) & 63;
    const int g = bid & 3;
    const int tid = threadIdx.x;
    const int lane = tid & 63, wv = tid >> 6;
    const int n16 = lane & 15, quad = lane >> 4;
    const int xr = n16 & (NCH - 1);

    // stage-1 stats finalize (for inline normalization of the raw gather)
    if (tid < 64) {
        int c0i = 2 * tid, c1i = 2 * tid + 1;
        float s0 = 0.f, q0 = 0.f, s1 = 0.f, q1 = 0.f;
#pragma unroll
        for (int r = 0; r < 8; ++r) {
            s0 += pr_in[r * 256 + c0i];
            q0 += pr_in[r * 256 + 128 + c0i];
            s1 += pr_in[r * 256 + c1i];
            q1 += pr_in[r * 256 + 128 + c1i];
        }
        float m0v = s0 / 65536.f, m1v = s1 / 65536.f;
        float r0 = rsqrtf(q0 / 65536.f - m0v * m0v + 1e-5f);
        float r1 = rsqrtf(q1 / 65536.f - m1v * m1v + 1e-5f);
        cst[tid] = f2h2(r0, r1);
        cst[64 + tid] = f2h2(-m0v * r0, -m1v * r1);
    }

    // pixel p in [0,64): row = 2*rp + (p>>5), col = g*32 + (p&31)
    for (int r = tid; r < PIX * 9; r += 256) {
        int p = r & (PIX - 1), k = r >> 6;
        int row = 2 * rp + (p >> 5), col = g * 32 + (p & 31);
        int oi = ((b * 9 + k) << 14) + (row << 7) + col;
        float py = (float)(row + k / 3 - 1) + dyb[oi];
        float px = (float)(col + k % 3 - 1) + dxb[oi];
        float mv = mob[oi];
        float y0f = floorf(py), x0f = floorf(px);
        float wy = py - y0f, wx = px - x0f;
        int y0 = (int)y0f, x0 = (int)x0f;
        int y1 = y0 + 1, x1 = x0 + 1;
        float f00 = (1.f - wy) * (1.f - wx) *
                    (((unsigned)y0 < 128u && (unsigned)x0 < 128u) ? mv : 0.f);
        float f01 = (1.f - wy) * wx *
                    (((unsigned)y0 < 128u && (unsigned)x1 < 128u) ? mv : 0.f);
        float f10 = wy * (1.f - wx) *
                    (((unsigned)y1 < 128u && (unsigned)x0 < 128u) ? mv : 0.f);
        float f11 = wy * wx *
                    (((unsigned)y1 < 128u && (unsigned)x1 < 128u) ? mv : 0.f);
        int cy0 = min(max(y0, 0), 127), cy1 = min(max(y1, 0), 127);
        int cx0 = min(max(x0, 0), 127), cx1 = min(max(x1, 0), 127);
        int base00 = (((b << 14) + (cy0 << 7) + cx0)) * C;
        int flags = ((cy1 != cy0) ? 2 : 0) | ((cx1 != cx0) ? 1 : 0);
        int s = p * 9 + k;
        tbl[s] = base00 | flags;
        twl[2 * s] = f2h2(f00, f01);
        twl[2 * s + 1] = f2h2(f10, f11);
    }
    __syncthreads();

    // per-thread channel-norm constants (cc = tid % NCC is loop-invariant)
    const int ccf = tid & (NCC - 1);
    const h8 Rv = *(const h8*)&cst[ccf * 4];
    const h8 Nv = *(const h8*)&cst[64 + ccf * 4];

    auto issue_loads = [&](int kc, int it0, uint4 (&q)[HNIT][4],
                           uint2 (&fw)[HNIT]) {
#pragma unroll
        for (int j = 0; j < HNIT; ++j) {
            int e = (it0 + j) * 256 + tid;
            int p = e / NCC, cc = e % NCC;
            int s = p * 9 + kc;
            int ent = tbl[s];
            fw[j] = *(const uint2*)&twl[2 * s];
            int base = ent & ~3;
            int dxo = (ent & 1) ? C : 0;
            int dyo = (ent & 2) ? (C << 7) : 0;
            const ushort* pp = xh + (size_t)base + cc * 8;
            q[j][0] = *(const uint4*)(pp);
            q[j][1] = *(const uint4*)(pp + dxo);
            q[j][2] = *(const uint4*)(pp + dyo);
            q[j][3] = *(const uint4*)(pp + dyo + dxo);
        }
    };
    auto interp_write = [&](ushort* dst, int it0, uint4 (&q)[HNIT][4],
                            uint2 (&fw)[HNIT]) {
#pragma unroll
        for (int j = 0; j < HNIT; ++j) {
            int e = (it0 + j) * 256 + tid;
            int p = e / NCC, cc = e % NCC;
            h2 w01, w23;
            __builtin_memcpy(&w01, &fw[j].x, 4);
            __builtin_memcpy(&w23, &fw[j].y, 4);
            h8 F0 = {w01.x, w01.x, w01.x, w01.x, w01.x, w01.x, w01.x, w01.x};
            h8 F1 = {w01.y, w01.y, w01.y, w01.y, w01.y, w01.y, w01.y, w01.y};
            h8 F2 = {w23.x, w23.x, w23.x, w23.x, w23.x, w23.x, w23.x, w23.x};
            h8 F3 = {w23.y, w23.y, w23.y, w23.y, w23.y, w23.y, w23.y, w23.y};
            h8 a0, a1, a2, a3;
            __builtin_memcpy(&a0, &q[j][0], 16);
            __builtin_memcpy(&a1, &q[j][1], 16);
            __builtin_memcpy(&a2, &q[j][2], 16);
            __builtin_memcpy(&a3, &q[j][3], 16);
            a0 = nrelu8(a0, Rv, Nv);
            a1 = nrelu8(a1, Rv, Nv);
            a2 = nrelu8(a2, Rv, Nv);
            a3 = nrelu8(a3, Rv, Nv);
            h8 v = a0 * F0 + a1 * F1 + a2 * F2 + a3 * F3;
            uint4 ov;
            __builtin_memcpy(&ov, &v, 16);
            int ccs = cc ^ (p & (NCH - 1));
            *(uint4*)&dst[p * C + ccs * 8] = ov;
        }
    };

    f32x4 acc[4][2];
#pragma unroll
    for (int mt = 0; mt < 4; ++mt)
#pragma unroll
        for (int nt = 0; nt < 2; ++nt) acc[mt][nt] = (f32x4){0.f, 0.f, 0.f, 0.f};

    const ushort* bbase[2];
#pragma unroll
    for (int nt = 0; nt < 2; ++nt)
        bbase[nt] = wt + (size_t)(wv * 32 + nt * 16 + n16) * KP + quad * 8;

    auto mfma_run = [&](const ushort* ab, int kc, int s0, int s1) {
#pragma unroll
        for (int s = s0; s < s1; ++s) {
            h8 av[4], bv[2];
            int ch = (s * 4 + quad) ^ xr;
#pragma unroll
            for (int mt = 0; mt < 4; ++mt)
                av[mt] = *(const h8*)(ab + (mt * 16 + n16) * C + ch * 8);
#pragma unroll
            for (int nt = 0; nt < 2; ++nt)
                bv[nt] = *(const h8*)(bbase[nt] + kc * CPW + s * 32);
#pragma unroll
            for (int mt = 0; mt < 4; ++mt)
#pragma unroll
                for (int nt = 0; nt < 2; ++nt)
                    acc[mt][nt] = __builtin_amdgcn_mfma_f32_16x16x32_f16(
                        av[mt], bv[nt], acc[mt][nt], 0, 0, 0);
        }
    };

    {
        uint4 q[HNIT][4];
        uint2 fw[HNIT];
        issue_loads(0, 0, q, fw);
        interp_write(abuf0, 0, q, fw);
        issue_loads(0, HNIT, q, fw);
        interp_write(abuf0, HNIT, q, fw);
    }
    __syncthreads();

#pragma unroll 1
    for (int kc = 0; kc < 9; ++kc) {
        const ushort* ab = (kc & 1) ? abuf1 : abuf0;
        ushort* dst = (kc & 1) ? abuf0 : abuf1;
        uint4 q[HNIT][4];
        uint2 fw[HNIT];
        if (kc < 8) issue_loads(kc + 1, 0, q, fw);
        __builtin_amdgcn_s_setprio(1);
        mfma_run(ab, kc, 0, SH);
        __builtin_amdgcn_s_setprio(0);
        if (kc < 8) {
            interp_write(dst, 0, q, fw);
            issue_loads(kc + 1, HNIT, q, fw);
        }
        __builtin_amdgcn_s_setprio(1);
        mfma_run(ab, kc, SH, C / 32);
        __builtin_amdgcn_s_setprio(0);
        if (kc < 8) interp_write(dst, HNIT, q, fw);
        __syncthreads();
    }

    // ---- epilogue: stats from full-res tile + block-local 2x2 pool ----
    float* sm = (float*)smem_raw;
    constexpr int SROW = PIX + 1;
#pragma unroll
    for (int mt = 0; mt < 4; ++mt)
#pragma unroll
        for (int nt = 0; nt < 2; ++nt) {
            int o = wv * 32 + nt * 16 + n16;
            int mb = mt * 16 + quad * 4;
#pragma unroll
            for (int r = 0; r < 4; ++r) sm[o * SROW + mb + r] = acc[mt][nt][r];
        }
    __syncthreads();
    {
        int o = tid >> 1, half = tid & 1;
        const float* so = sm + o * SROW;
        const float* sp = so + half * 32;
        float s = 0.f, qq = 0.f;
#pragma unroll
        for (int i = 0; i < 32; i += 4) {
            float4 v = make_float4(sp[i], sp[i + 1], sp[i + 2], sp[i + 3]);
            s += v.x + v.y + v.z + v.w;
            qq += v.x * v.x + v.y * v.y + v.z * v.z + v.w * v.w;
        }
        s += __shfl_down(s, 1, 64);
        qq += __shfl_down(qq, 1, 64);
        if (half == 0) {
            float* pr = praw + (blockIdx.x & 7) * 256;
            atomicAdd(&pr[o], s);
            atomicAdd(&pr[128 + o], qq);
        }
        // pool: rows are px [0,32) and [32,64); pooled cols pc = half*8 + i
        float4 pv0, pv1;
#pragma unroll
        for (int i = 0; i < 8; ++i) {
            int pc = half * 8 + i;
            float m0v = fmaxf(so[2 * pc], so[2 * pc + 1]);
            float m1v = fmaxf(so[32 + 2 * pc], so[32 + 2 * pc + 1]);
            float m = fmaxf(m0v, m1v);
            if (i < 4) ((float*)&pv0)[i] = m;
            else ((float*)&pv1)[i - 4] = m;
        }
        float* dp = pout + (((size_t)(b * 128 + o)) << 12) + rp * 64 + g * 16 +
                    half * 8;
        *(float4*)(dp) = pv0;
        *(float4*)(dp + 4) = pv1;
    }
}

// ---- pooled normalize: out = relu((pout - mean) * rstd) ----
__global__ __launch_bounds__(256) void pool_norm(const float* __restrict__ pout,
                                                 const float* __restrict__ praw,
                                                 float* __restrict__ out) {
    __shared__ float lstats[256];
    if (threadIdx.x < 128) {
        int c = threadIdx.x;
        float s = 0.f, q = 0.f;
#pragma unroll
        for (int r = 0; r < 8; ++r) {
            s += praw[r * 256 + c];
            q += praw[r * 256 + 128 + c];
        }
        float mean = s / 65536.f;
        float var = q / 65536.f - mean * mean;
        lstats[c] = mean;
        lstats[128 + c] = rsqrtf(var + 1e-5f);
    }
    __syncthreads();
    int i = blockIdx.x * 256 + threadIdx.x;  // float4 index, total 524288
    int c = (i >> 10) & 127;
    float mean = lstats[c], rstd = lstats[128 + c];
    float4 v = ((const float4*)pout)[i];
    v.x = fmaxf(0.f, (v.x - mean) * rstd);
    v.y = fmaxf(0.f, (v.y - mean) * rstd);
    v.z = fmaxf(0.f, (v.z - mean) * rstd);
    v.w = fmaxf(0.f, (v.w - mean) * rstd);
    ((float4*)out)[i] = v;
}

extern "C" void kernel_launch(void* const* d_in, const int* in_sizes, int n_in,
                              void* d_out, int out_size, void* d_ws,
                              size_t ws_size, hipStream_t stream) {
    (void)in_sizes;
    (void)n_in;
    (void)out_size;
    (void)ws_size;
    const float* x = (const float*)d_in[0];
    const float* w_off1 = (const float*)d_in[1];
    const float* b_off1 = (const float*)d_in[2];
    const float* w_mod1 = (const float*)d_in[3];
    const float* b_mod1 = (const float*)d_in[4];
    const float* w1 = (const float*)d_in[5];
    const float* w_off2 = (const float*)d_in[6];
    const float* b_off2 = (const float*)d_in[7];
    const float* w_mod2 = (const float*)d_in[8];
    const float* b_mod2 = (const float*)d_in[9];
    const float* w2 = (const float*)d_in[10];
    float* out = (float*)d_out;
    float* ws = (float*)d_ws;

    // KP1 = 672 (C=64, CP=72), KP2 = 1248 (C=128, CP=136)
    ushort* Wt1 = (ushort*)ws;                            // 86016 ush = 43008 f
    ushort* Wt2 = (ushort*)(ws + 43008);                  // 159744 ush = 79872 f
    ushort* Wo1 = (ushort*)(ws + 43008 + 79872);          // need 18432 ush
    ushort* Wo2 = (ushort*)(ws + 43008 + 79872 + 16384);  // need 36864 ush
    float* dyb = ws + 172032;
    float* dxb = dyb + 589824;
    float* mob = dxb + 589824;
    float* hbuf = mob + 589824;      // h1 RAW fp16 NHWC (lives through stage 2)
    float* xhf = hbuf + 8388608;     // 2097152 f: x as NHWC fp16
    float* h1hf = xhf + 2097152;     // 4194304 f: now pooled raw max (2M used)
    float* praw1 = h1hf + 4194304;   // 2048 (8 replicas x 256) stage-1 stats
    float* praw2 = praw1 + 2048;     // 2048 stage-2 stats
    ushort* xh = (ushort*)xhf;
    ushort* hb = (ushort*)hbuf;

    // ---- stage 1 (cvt + weight prep merged into one launch) ----
    cvt_prep<64><<<2200, 256, 0, stream>>>(x, (unsigned*)xh, w1, w2, w_off1,
                                           w_mod1, w_off2, w_mod2, Wt1, Wt2,
                                           Wo1, Wo2);
    offmod_nhwc<64, false><<<1024, 256, 0, stream>>>(
        xh, Wo1, b_off1, b_mod1, dyb, dxb, mob, praw1, praw1);
    deform_mfma3<64><<<1024, 256, 0, stream>>>(xh, dyb, dxb, mob, Wt1,
                                               (unsigned*)hbuf, praw1);

    // ---- stage 2 (bn of h1 fused inline: consumers read RAW hbuf + praw1) ----
    offmod_nhwc<128, true><<<1024, 256, 0, stream>>>(
        hb, Wo2, b_off2, b_mod2, dyb, dxb, mob, praw2, praw1);
    deform_mfma3p<128><<<1024, 256, 0, stream>>>(hb, dyb, dxb, mob, Wt2, h1hf,
                                                 praw2, praw1);
    pool_norm<<<2048, 256, 0, stream>>>(h1hf, praw2, out);
}